// Round 4
// baseline (368.439 us; speedup 1.0000x reference)
//
#include <hip/hip_runtime.h>

#define N_PART 2048
#define NP_OBJ 2000
#define NREL 16384

__device__ __forceinline__ int clampi(int v) {
  return v < 0 ? 0 : (v >= N_PART ? N_PART - 1 : v);
}

// ---- zero a float buffer -------------------------------------------------
__global__ __launch_bounds__(256) void k_zero(float* __restrict__ p, int n) {
  int i = blockIdx.x * 256 + threadIdx.x;
  if (i < n) p[i] = 0.f;
}
__global__ __launch_bounds__(256) void k_izero(int* __restrict__ p, int n) {
  int i = blockIdx.x * 256 + threadIdx.x;
  if (i < n) p[i] = 0;
}

// ---- extract one-hot indices from Rr/Rs (f32 rows of length 2048) --------
__global__ __launch_bounds__(256) void k_extract_idx(
    const float* __restrict__ Rr, const float* __restrict__ Rs,
    int* __restrict__ recv, int* __restrict__ send) {
  int b = blockIdx.x;
  bool isR = (b < NREL);
  int row = isR ? b : b - NREL;
  const float* p = (isR ? Rr : Rs) + (size_t)row * N_PART;
  int* out = (isR ? recv : send) + row;
  int t = threadIdx.x;
#pragma unroll
  for (int half = 0; half < 2; ++half) {
    int idx = half * 256 + t;                 // float4 index, 512 total
    float4 u = ((const float4*)p)[idx];
    int base = idx * 4;
    if (u.x != 0.f) *out = base + 0;
    if (u.y != 0.f) *out = base + 1;
    if (u.z != 0.f) *out = base + 2;
    if (u.w != 0.f) *out = base + 3;
  }
}

// ---- build p_inputs [2048][16] f32 (col 15 = pad) ------------------------
__global__ void k_pinputs(const float* __restrict__ state, const float* __restrict__ attrs,
                          const float* __restrict__ action, const float* __restrict__ phys,
                          float* __restrict__ pin) {
  int i = blockIdx.x * blockDim.x + threadIdx.x;
  if (i >= N_PART) return;
  float s0[3], s1[3], s2[3];
#pragma unroll
  for (int d = 0; d < 3; ++d) {
    s0[d] = state[(0 * N_PART + i) * 3 + d];
    s1[d] = state[(1 * N_PART + i) * 3 + d];
    s2[d] = state[(2 * N_PART + i) * 3 + d];
  }
  float* o = pin + (size_t)i * 16;
  o[0] = attrs[i * 2 + 0];
  o[1] = attrs[i * 2 + 1];
#pragma unroll
  for (int d = 0; d < 3; ++d) {
    o[2 + d] = s1[d] - s0[d];
    o[5 + d] = s2[d] - s1[d];
    o[8 + d] = s2[d];
  }
  o[11] = (i < NP_OBJ) ? phys[i] : 0.f;
#pragma unroll
  for (int d = 0; d < 3; ++d) o[12 + d] = action[i * 3 + d];
  o[15] = 0.f;
}

// ---- generic small GEMM: out[M][128] = act(A@W + b (+resid)) -------------
// MODE 0: plain A (lda).  MODE 2: A row i = [A[i](128) | srcB[i](128)]
template <int MODE>
__global__ __launch_bounds__(256) void k_gemm(
    const float* __restrict__ A, int lda, int K, int M,
    const float* __restrict__ W, const float* __restrict__ bias,
    const float* __restrict__ resid, float* __restrict__ out, int relu,
    const float* __restrict__ srcB) {
  __shared__ float a_lds[64][36];
  __shared__ float w_lds[64][128];
  int tid = threadIdx.x;
  int c  = tid & 31;
  int rg = tid >> 5;
  int row0 = blockIdx.x * 32;
  float acc[4][4] = {};
  for (int k0 = 0; k0 < K; k0 += 64) {
#pragma unroll
    for (int i = 0; i < 8; ++i) {
      int off = i * 1024 + tid * 4;
      int kk = off >> 7, cc = off & 127;
      int k = k0 + kk;
      float4 wv = (k < K) ? *(const float4*)&W[(size_t)k * 128 + cc]
                          : make_float4(0.f, 0.f, 0.f, 0.f);
      *(float4*)&w_lds[kk][cc] = wv;
    }
#pragma unroll
    for (int i = 0; i < 8; ++i) {
      int idx = i * 256 + tid;
      int rr = idx >> 6, kk = idx & 63;
      int row = row0 + rr, k = k0 + kk;
      float v = 0.f;
      if (row < M && k < K) {
        if (MODE == 0) v = A[(size_t)row * lda + k];
        else           v = (k < 128) ? A[(size_t)row * 128 + k]
                                     : srcB[(size_t)row * 128 + (k - 128)];
      }
      a_lds[kk][rr] = v;
    }
    __syncthreads();
#pragma unroll 8
    for (int kk = 0; kk < 64; ++kk) {
      float4 w = *(const float4*)&w_lds[kk][c * 4];
      float4 a = *(const float4*)&a_lds[kk][rg * 4];
      acc[0][0] += a.x * w.x; acc[0][1] += a.x * w.y; acc[0][2] += a.x * w.z; acc[0][3] += a.x * w.w;
      acc[1][0] += a.y * w.x; acc[1][1] += a.y * w.y; acc[1][2] += a.y * w.z; acc[1][3] += a.y * w.w;
      acc[2][0] += a.z * w.x; acc[2][1] += a.z * w.y; acc[2][2] += a.z * w.z; acc[2][3] += a.z * w.w;
      acc[3][0] += a.w * w.x; acc[3][1] += a.w * w.y; acc[3][2] += a.w * w.z; acc[3][3] += a.w * w.w;
    }
    __syncthreads();
  }
  float4 bv = *(const float4*)&bias[c * 4];
  float bb[4] = {bv.x, bv.y, bv.z, bv.w};
#pragma unroll
  for (int rl = 0; rl < 4; ++rl) {
    int row = row0 + rg * 4 + rl;
    if (row < M) {
      float4 o;
      o.x = acc[rl][0] + bb[0]; o.y = acc[rl][1] + bb[1];
      o.z = acc[rl][2] + bb[2]; o.w = acc[rl][3] + bb[3];
      if (resid) {
        float4 rr = *(const float4*)&resid[(size_t)row * 128 + c * 4];
        o.x += rr.x; o.y += rr.y; o.z += rr.z; o.w += rr.w;
      }
      if (relu) {
        o.x = fmaxf(o.x, 0.f); o.y = fmaxf(o.y, 0.f);
        o.z = fmaxf(o.z, 0.f); o.w = fmaxf(o.w, 0.f);
      }
      *(float4*)&out[(size_t)row * 128 + c * 4] = o;
    }
  }
}

// ---- one MLP layer inside the fused relation encoder ---------------------
template <int K, bool LAST>
__device__ __forceinline__ void enc_layer(
    const float (*inT)[36], float (*outT)[36], float (*w_lds)[128],
    const float* __restrict__ W, const float* __restrict__ bias,
    int tid, int c, int rg, float* __restrict__ gout, int row0) {
  float acc[4][4] = {};
  for (int k0 = 0; k0 < K; k0 += 64) {
    __syncthreads();  // protect w_lds (prev users done) and inT (fully written)
#pragma unroll
    for (int i = 0; i < 8; ++i) {
      int off = i * 1024 + tid * 4;
      int kk = off >> 7, cc = off & 127;
      int k = k0 + kk;
      float4 wv = (k < K) ? *(const float4*)&W[(size_t)k * 128 + cc]
                          : make_float4(0.f, 0.f, 0.f, 0.f);
      *(float4*)&w_lds[kk][cc] = wv;
    }
    __syncthreads();
#pragma unroll 8
    for (int kk = 0; kk < 64; ++kk) {
      float4 w = *(const float4*)&w_lds[kk][c * 4];
      float4 a = *(const float4*)&inT[k0 + kk][rg * 4];
      acc[0][0] += a.x * w.x; acc[0][1] += a.x * w.y; acc[0][2] += a.x * w.z; acc[0][3] += a.x * w.w;
      acc[1][0] += a.y * w.x; acc[1][1] += a.y * w.y; acc[1][2] += a.y * w.z; acc[1][3] += a.y * w.w;
      acc[2][0] += a.z * w.x; acc[2][1] += a.z * w.y; acc[2][2] += a.z * w.z; acc[2][3] += a.z * w.w;
      acc[3][0] += a.w * w.x; acc[3][1] += a.w * w.y; acc[3][2] += a.w * w.z; acc[3][3] += a.w * w.w;
    }
  }
  float4 bv = *(const float4*)&bias[c * 4];
  float bb[4] = {bv.x, bv.y, bv.z, bv.w};
#pragma unroll
  for (int rl = 0; rl < 4; ++rl) {
    int rr = rg * 4 + rl;
#pragma unroll
    for (int j = 0; j < 4; ++j) {
      float v = fmaxf(acc[rl][j] + bb[j], 0.f);
      if (LAST) gout[(size_t)(row0 + rr) * 128 + c * 4 + j] = v;
      else      outT[c * 4 + j][rr] = v;
    }
  }
}

// ---- fused 3-layer relation encoder (builds rel_inputs in LDS) -----------
__global__ __launch_bounds__(256) void k_rel_enc(
    const float* __restrict__ pin, const int* __restrict__ recv,
    const int* __restrict__ send, const float* __restrict__ pinst,
    const float* __restrict__ w0, const float* __restrict__ b0,
    const float* __restrict__ w1, const float* __restrict__ b1,
    const float* __restrict__ w2, const float* __restrict__ b2,
    float* __restrict__ RE) {
  __shared__ float hA[128][36];
  __shared__ float hB[128][36];
  __shared__ float w_lds[64][128];
  int tid = threadIdx.x;
  int c = tid & 31, rg = tid >> 5;
  int row0 = blockIdx.x * 32;

  // build layer-0 input transposed: hA[k][rr], k<44 real, 44..63 zero
  for (int idx = tid; idx < 64 * 32; idx += 256) {
    int kk = idx >> 5, rr = idx & 31;
    int e = row0 + rr;
    int r = clampi(recv[e]), s = clampi(send[e]);
    const float* pr = pin + (size_t)r * 16;
    const float* ps = pin + (size_t)s * 16;
    float v = 0.f;
    if (kk < 15) v = pr[kk];
    else if (kk < 30) v = ps[kk - 15];
    else if (kk < 32) v = pr[kk - 30];
    else if (kk < 34) v = ps[kk - 32];
    else if (kk == 34) {
      float gd = 0.f;
#pragma unroll
      for (int j = 0; j < 8; ++j) {
        float gr = (r < NP_OBJ) ? pinst[r * 8 + j] : 0.f;
        float gs = (s < NP_OBJ) ? pinst[s * 8 + j] : 0.f;
        gd += fabsf(gr - gs);
      }
      v = gd;
    } else if (kk < 44) {
      v = pr[2 + kk - 35] - ps[2 + kk - 35];
    }
    hA[kk][rr] = v;
  }

  enc_layer<44, false>(hA, hB, w_lds, w0, b0, tid, c, rg, nullptr, row0);
  enc_layer<128, false>(hB, hA, w_lds, w1, b1, tid, c, rg, nullptr, row0);
  enc_layer<128, true>(hA, hB, w_lds, w2, b2, tid, c, rg, RE, row0);
}

// ---- fused relation propagator: erel GEMM (K=384) + scatter-add ----------
__global__ __launch_bounds__(256) void k_prop_rel(
    const float* __restrict__ RE, const float* __restrict__ eff,
    const int* __restrict__ recv, const int* __restrict__ send,
    const float* __restrict__ W, const float* __restrict__ bias,
    float* __restrict__ agg) {
  __shared__ float a_lds[64][36];
  __shared__ float w_lds[64][128];
  int tid = threadIdx.x;
  int c = tid & 31, rg = tid >> 5;
  int row0 = blockIdx.x * 32;
  float acc[4][4] = {};
  for (int k0 = 0; k0 < 384; k0 += 64) {
#pragma unroll
    for (int i = 0; i < 8; ++i) {
      int off = i * 1024 + tid * 4;
      int kk = off >> 7, cc = off & 127;
      int k = k0 + kk;
      *(float4*)&w_lds[kk][cc] = *(const float4*)&W[(size_t)k * 128 + cc];
    }
#pragma unroll
    for (int i = 0; i < 8; ++i) {
      int idx = i * 256 + tid;
      int rr = idx >> 6, kk = idx & 63;
      int row = row0 + rr, k = k0 + kk;
      float v;
      if (k < 128)      v = RE[(size_t)row * 128 + k];
      else if (k < 256) v = eff[(size_t)clampi(recv[row]) * 128 + (k - 128)];
      else              v = eff[(size_t)clampi(send[row]) * 128 + (k - 256)];
      a_lds[kk][rr] = v;
    }
    __syncthreads();
#pragma unroll 8
    for (int kk = 0; kk < 64; ++kk) {
      float4 w = *(const float4*)&w_lds[kk][c * 4];
      float4 a = *(const float4*)&a_lds[kk][rg * 4];
      acc[0][0] += a.x * w.x; acc[0][1] += a.x * w.y; acc[0][2] += a.x * w.z; acc[0][3] += a.x * w.w;
      acc[1][0] += a.y * w.x; acc[1][1] += a.y * w.y; acc[1][2] += a.y * w.z; acc[1][3] += a.y * w.w;
      acc[2][0] += a.z * w.x; acc[2][1] += a.z * w.y; acc[2][2] += a.z * w.z; acc[2][3] += a.z * w.w;
      acc[3][0] += a.w * w.x; acc[3][1] += a.w * w.y; acc[3][2] += a.w * w.z; acc[3][3] += a.w * w.w;
    }
    __syncthreads();
  }
  float4 bv = *(const float4*)&bias[c * 4];
  float bb[4] = {bv.x, bv.y, bv.z, bv.w};
#pragma unroll
  for (int rl = 0; rl < 4; ++rl) {
    int row = row0 + rg * 4 + rl;
    int dst = clampi(recv[row]);
    float* ap = agg + (size_t)dst * 128 + c * 4;
#pragma unroll
    for (int j = 0; j < 4; ++j) {
      float v = fmaxf(acc[rl][j] + bb[j], 0.f);
      atomicAdd(&ap[j], v);
    }
  }
}

// ---- final tiny GEMV + clip + outputs ------------------------------------
__global__ void k_predict(const float* __restrict__ h2, const float* __restrict__ w2,
                          const float* __restrict__ b2, const float* __restrict__ state,
                          float* __restrict__ out) {
  int i = blockIdx.x * blockDim.x + threadIdx.x;
  if (i >= NP_OBJ) return;
  float acc0 = b2[0], acc1 = b2[1], acc2 = b2[2];
  const float* h = h2 + (size_t)i * 128;
#pragma unroll 8
  for (int k = 0; k < 128; ++k) {
    float hv = h[k];
    acc0 += hv * w2[k * 3 + 0];
    acc1 += hv * w2[k * 3 + 1];
    acc2 += hv * w2[k * 3 + 2];
  }
  float m[3] = {acc0, acc1, acc2};
#pragma unroll
  for (int d = 0; d < 3; ++d) {
    float cl = fminf(fmaxf(m[d], -100.f), 100.f);
    float pos = state[(size_t)(2 * N_PART + i) * 3 + d] + cl;
    out[i * 3 + d] = pos;
    out[NP_OBJ * 3 + i * 3 + d] = m[d];
  }
}

extern "C" void kernel_launch(void* const* d_in, const int* in_sizes, int n_in,
                              void* d_out, int out_size, void* d_ws, size_t ws_size,
                              hipStream_t stream) {
  const float* state  = (const float*)d_in[0];
  const float* attrs  = (const float*)d_in[1];
  const float* Rr     = (const float*)d_in[2];
  const float* Rs     = (const float*)d_in[3];
  const float* pinst  = (const float*)d_in[4];
  const float* action = (const float*)d_in[5];
  const float* phys   = (const float*)d_in[6];
  const float* pe_w0 = (const float*)d_in[7];  const float* pe_b0 = (const float*)d_in[8];
  const float* pe_w1 = (const float*)d_in[9];  const float* pe_b1 = (const float*)d_in[10];
  const float* pe_w2 = (const float*)d_in[11]; const float* pe_b2 = (const float*)d_in[12];
  const float* re_w0 = (const float*)d_in[13]; const float* re_b0 = (const float*)d_in[14];
  const float* re_w1 = (const float*)d_in[15]; const float* re_b1 = (const float*)d_in[16];
  const float* re_w2 = (const float*)d_in[17]; const float* re_b2 = (const float*)d_in[18];
  const float* pp_w  = (const float*)d_in[19]; const float* pp_b  = (const float*)d_in[20];
  const float* rp_w  = (const float*)d_in[21]; const float* rp_b  = (const float*)d_in[22];
  const float* np_w0 = (const float*)d_in[23]; const float* np_b0 = (const float*)d_in[24];
  const float* np_w1 = (const float*)d_in[25]; const float* np_b1 = (const float*)d_in[26];
  const float* np_w2 = (const float*)d_in[27]; const float* np_b2 = (const float*)d_in[28];

  char* ws = (char*)d_ws;
  size_t off = 0;
  auto alloc = [&](size_t b) { size_t o = off; off += (b + 255) & ~(size_t)255; return o; };
  int*   recv = (int*)(ws + alloc(NREL * 4));
  int*   send = (int*)(ws + alloc(NREL * 4));
  float* pin  = (float*)(ws + alloc((size_t)N_PART * 16 * 4));
  float* t0   = (float*)(ws + alloc((size_t)N_PART * 128 * 4));
  float* t1   = (float*)(ws + alloc((size_t)N_PART * 128 * 4));
  float* PE   = (float*)(ws + alloc((size_t)N_PART * 128 * 4));
  float* RE   = (float*)(ws + alloc((size_t)NREL * 128 * 4));
  float* agg  = (float*)(ws + alloc((size_t)N_PART * 128 * 4));
  float* eA   = (float*)(ws + alloc((size_t)N_PART * 128 * 4));
  float* eB   = (float*)(ws + alloc((size_t)N_PART * 128 * 4));
  if (off > ws_size) return;  // diagnostic guard: fail numerically, not fault

  k_izero<<<(2 * NREL + 255) / 256, 256, 0, stream>>>(recv, 2 * NREL);  // recv+send contiguous
  k_extract_idx<<<2 * NREL, 256, 0, stream>>>(Rr, Rs, recv, send);
  k_pinputs<<<(N_PART + 255) / 256, 256, 0, stream>>>(state, attrs, action, phys, pin);

  // particle encoder
  k_gemm<0><<<N_PART / 32, 256, 0, stream>>>(pin, 16, 15, N_PART, pe_w0, pe_b0, nullptr, t0, 1, nullptr);
  k_gemm<0><<<N_PART / 32, 256, 0, stream>>>(t0, 128, 128, N_PART, pe_w1, pe_b1, nullptr, t1, 1, nullptr);
  k_gemm<0><<<N_PART / 32, 256, 0, stream>>>(t1, 128, 128, N_PART, pe_w2, pe_b2, nullptr, PE, 1, nullptr);

  // fused relation encoder
  k_rel_enc<<<NREL / 32, 256, 0, stream>>>(pin, recv, send, pinst,
                                           re_w0, re_b0, re_w1, re_b1, re_w2, re_b2, RE);

  // propagation x3
  float* ecur = PE;
  float* enext = eA;
  for (int step = 0; step < 3; ++step) {
    k_zero<<<(N_PART * 128 + 255) / 256, 256, 0, stream>>>(agg, N_PART * 128);
    k_prop_rel<<<NREL / 32, 256, 0, stream>>>(RE, ecur, recv, send, rp_w, rp_b, agg);
    k_gemm<2><<<N_PART / 32, 256, 0, stream>>>(PE, 128, 256, N_PART, pp_w, pp_b, ecur, enext, 1, agg);
    ecur = enext;
    enext = (ecur == eA) ? eB : eA;
  }

  // predictor
  float* h1 = t0;
  float* h2 = t1;
  k_gemm<0><<<(NP_OBJ + 31) / 32, 256, 0, stream>>>(ecur, 128, 128, NP_OBJ, np_w0, np_b0, nullptr, h1, 1, nullptr);
  k_gemm<0><<<(NP_OBJ + 31) / 32, 256, 0, stream>>>(h1, 128, 128, NP_OBJ, np_w1, np_b1, nullptr, h2, 1, nullptr);
  k_predict<<<(NP_OBJ + 255) / 256, 256, 0, stream>>>(h2, np_w2, np_b2, state, (float*)d_out);
}

// Round 5
// 291.008 us; speedup vs baseline: 1.2661x; 1.2661x over previous
//
#include <hip/hip_runtime.h>

#define N_PART 2048
#define NP_OBJ 2000
#define NREL 16384

typedef __attribute__((ext_vector_type(8))) short bf16x8;
typedef __attribute__((ext_vector_type(4))) float f32x4;

__device__ __forceinline__ int clampi(int v) {
  return v < 0 ? 0 : (v >= N_PART ? N_PART - 1 : v);
}
__device__ __forceinline__ unsigned short f2b(float f) {
  union { float f; unsigned int u; } v; v.f = f;
  return (unsigned short)((v.u + 0x7fffu + ((v.u >> 16) & 1u)) >> 16);  // RNE
}

// ---- zero helpers --------------------------------------------------------
__global__ __launch_bounds__(256) void k_zero(float* __restrict__ p, int n) {
  int i = blockIdx.x * 256 + threadIdx.x;
  if (i < n) p[i] = 0.f;
}
__global__ __launch_bounds__(256) void k_izero(int* __restrict__ p, int n) {
  int i = blockIdx.x * 256 + threadIdx.x;
  if (i < n) p[i] = 0;
}

// ---- extract one-hot indices: one wave per row ---------------------------
__global__ __launch_bounds__(256) void k_extract_idx(
    const float* __restrict__ Rr, const float* __restrict__ Rs,
    int* __restrict__ recv, int* __restrict__ send) {
  int wid = blockIdx.x * 4 + (threadIdx.x >> 6);
  int lane = threadIdx.x & 63;
  bool isR = wid < NREL;
  int row = isR ? wid : wid - NREL;
  const uint4* p = (const uint4*)((isR ? Rr : Rs) + (size_t)row * N_PART);
  int* out = (isR ? recv : send) + row;
#pragma unroll
  for (int j = 0; j < 8; ++j) {
    int idx = j * 64 + lane;
    uint4 u = p[idx];
    int base = idx * 4;
    if (u.x) *out = base;
    if (u.y) *out = base + 1;
    if (u.z) *out = base + 2;
    if (u.w) *out = base + 3;
  }
}

// ---- build p_inputs [2048][16] f32 (col 15 = pad) ------------------------
__global__ void k_pinputs(const float* __restrict__ state, const float* __restrict__ attrs,
                          const float* __restrict__ action, const float* __restrict__ phys,
                          float* __restrict__ pin) {
  int i = blockIdx.x * blockDim.x + threadIdx.x;
  if (i >= N_PART) return;
  float s0[3], s1[3], s2[3];
#pragma unroll
  for (int d = 0; d < 3; ++d) {
    s0[d] = state[(0 * N_PART + i) * 3 + d];
    s1[d] = state[(1 * N_PART + i) * 3 + d];
    s2[d] = state[(2 * N_PART + i) * 3 + d];
  }
  float* o = pin + (size_t)i * 16;
  o[0] = attrs[i * 2 + 0];
  o[1] = attrs[i * 2 + 1];
#pragma unroll
  for (int d = 0; d < 3; ++d) {
    o[2 + d] = s1[d] - s0[d];
    o[5 + d] = s2[d] - s1[d];
    o[8 + d] = s2[d];
  }
  o[11] = (i < NP_OBJ) ? phys[i] : 0.f;
#pragma unroll
  for (int d = 0; d < 3; ++d) o[12 + d] = action[i * 3 + d];
  o[15] = 0.f;
}

// ---- transpose 9 weight matrices W[K][128] -> WT[128][Kp] (zero-pad) -----
struct TWSeg { const float* src; float* dst; int K; int Kp; };
struct TW9 { TWSeg s[9]; };
__global__ __launch_bounds__(64) void k_twT(TW9 t) {
  int m = blockIdx.x >> 7;
  int n = blockIdx.x & 127;
  TWSeg sg = t.s[m];
  for (int k = threadIdx.x; k < sg.Kp; k += 64) {
    float v = (k < sg.K) ? sg.src[(size_t)k * 128 + n] : 0.f;
    sg.dst[(size_t)n * sg.Kp + k] = v;
  }
}

// ---- f32 GEMM for the tiny K=15 particle-encoder layer 0 -----------------
__global__ __launch_bounds__(256) void k_gemm0(
    const float* __restrict__ A, int lda, int K, int M,
    const float* __restrict__ W, const float* __restrict__ bias,
    float* __restrict__ out) {
  __shared__ float a_lds[64][36];
  __shared__ float w_lds[64][128];
  int tid = threadIdx.x;
  int c = tid & 31, rg = tid >> 5;
  int row0 = blockIdx.x * 32;
  float acc[4][4] = {};
  for (int k0 = 0; k0 < K; k0 += 64) {
#pragma unroll
    for (int i = 0; i < 8; ++i) {
      int off = i * 1024 + tid * 4;
      int kk = off >> 7, cc = off & 127;
      int k = k0 + kk;
      float4 wv = (k < K) ? *(const float4*)&W[(size_t)k * 128 + cc]
                          : make_float4(0.f, 0.f, 0.f, 0.f);
      *(float4*)&w_lds[kk][cc] = wv;
    }
#pragma unroll
    for (int i = 0; i < 8; ++i) {
      int idx = i * 256 + tid;
      int rr = idx >> 6, kk = idx & 63;
      int row = row0 + rr, k = k0 + kk;
      float v = 0.f;
      if (row < M && k < K) v = A[(size_t)row * lda + k];
      a_lds[kk][rr] = v;
    }
    __syncthreads();
#pragma unroll 8
    for (int kk = 0; kk < 64; ++kk) {
      float4 w = *(const float4*)&w_lds[kk][c * 4];
      float4 a = *(const float4*)&a_lds[kk][rg * 4];
      acc[0][0] += a.x * w.x; acc[0][1] += a.x * w.y; acc[0][2] += a.x * w.z; acc[0][3] += a.x * w.w;
      acc[1][0] += a.y * w.x; acc[1][1] += a.y * w.y; acc[1][2] += a.y * w.z; acc[1][3] += a.y * w.w;
      acc[2][0] += a.z * w.x; acc[2][1] += a.z * w.y; acc[2][2] += a.z * w.z; acc[2][3] += a.z * w.w;
      acc[3][0] += a.w * w.x; acc[3][1] += a.w * w.y; acc[3][2] += a.w * w.z; acc[3][3] += a.w * w.w;
    }
    __syncthreads();
  }
  float4 bv = *(const float4*)&bias[c * 4];
#pragma unroll
  for (int rl = 0; rl < 4; ++rl) {
    int row = row0 + rg * 4 + rl;
    if (row < M) {
      float4 o;
      o.x = fmaxf(acc[rl][0] + bv.x, 0.f);
      o.y = fmaxf(acc[rl][1] + bv.y, 0.f);
      o.z = fmaxf(acc[rl][2] + bv.z, 0.f);
      o.w = fmaxf(acc[rl][3] + bv.w, 0.f);
      *(float4*)&out[(size_t)row * 128 + c * 4] = o;
    }
  }
}

// ---- MFMA GEMM: out[M][128] = relu(A@W + b (+resid)) ---------------------
// A fragments: lane row = l&15, k = 8*(l>>4)+j. B: col = l&15 (from WT[n][k]).
// D: col = l&15, row = (l>>4)*4 + reg  [m89-verified]
// MODE 0: A[M][KTOT] plain.
// MODE 1: row e = [A(RE)[e] | srcB[recv[e]] | srcB[send[e]]]; epilogue: atomic scatter to agg.
// MODE 2: row i = [A[i] | srcB[i]].
template <int MODE, int KTOT>
__global__ __launch_bounds__(256) void k_mgemm(
    const float* __restrict__ A, const float* __restrict__ WT, int M,
    const float* __restrict__ bias, const float* __restrict__ resid,
    float* __restrict__ out, int relu,
    const float* __restrict__ srcB, const int* __restrict__ recv,
    const int* __restrict__ send, float* __restrict__ agg) {
  __shared__ unsigned short a_lds[64][72];
  __shared__ unsigned short wt_lds[128][72];
  int tid = threadIdx.x;
  int lane = tid & 63, w = tid >> 6;
  int wr0 = (w >> 1) * 32, wc0 = (w & 1) * 64;
  int row0 = blockIdx.x * 64;
  f32x4 acc[2][4] = {};
  for (int kc = 0; kc < KTOT; kc += 64) {
    __syncthreads();
    // stage A chunk [64 rows][64 k] -> bf16
#pragma unroll
    for (int i = 0; i < 4; ++i) {
      int idx = i * 256 + tid;
      int r = idx >> 4, kl = (idx & 15) * 4;
      int k = kc + kl;
      int grow = row0 + r;
      float4 v = make_float4(0.f, 0.f, 0.f, 0.f);
      if (MODE == 0) {
        if (grow < M) v = *(const float4*)&A[(size_t)grow * KTOT + k];
      } else if (MODE == 1) {
        if (k < 128)      v = *(const float4*)&A[(size_t)grow * 128 + k];
        else if (k < 256) v = *(const float4*)&srcB[(size_t)clampi(recv[grow]) * 128 + (k - 128)];
        else              v = *(const float4*)&srcB[(size_t)clampi(send[grow]) * 128 + (k - 256)];
      } else {
        if (k < 128) v = *(const float4*)&A[(size_t)grow * 128 + k];
        else         v = *(const float4*)&srcB[(size_t)grow * 128 + (k - 128)];
      }
      ushort4 b4; b4.x = f2b(v.x); b4.y = f2b(v.y); b4.z = f2b(v.z); b4.w = f2b(v.w);
      *(ushort4*)&a_lds[r][kl] = b4;
    }
    // stage WT chunk [128 n][64 k] -> bf16
#pragma unroll
    for (int i = 0; i < 8; ++i) {
      int idx = i * 256 + tid;
      int n = idx >> 4, kl = (idx & 15) * 4;
      float4 v = *(const float4*)&WT[(size_t)n * KTOT + kc + kl];
      ushort4 b4; b4.x = f2b(v.x); b4.y = f2b(v.y); b4.z = f2b(v.z); b4.w = f2b(v.w);
      *(ushort4*)&wt_lds[n][kl] = b4;
    }
    __syncthreads();
#pragma unroll
    for (int ks = 0; ks < 64; ks += 32) {
      bf16x8 a0 = *(const bf16x8*)&a_lds[wr0 + (lane & 15)][ks + 8 * (lane >> 4)];
      bf16x8 a1 = *(const bf16x8*)&a_lds[wr0 + 16 + (lane & 15)][ks + 8 * (lane >> 4)];
#pragma unroll
      for (int ct = 0; ct < 4; ++ct) {
        bf16x8 b = *(const bf16x8*)&wt_lds[wc0 + ct * 16 + (lane & 15)][ks + 8 * (lane >> 4)];
        acc[0][ct] = __builtin_amdgcn_mfma_f32_16x16x32_bf16(a0, b, acc[0][ct], 0, 0, 0);
        acc[1][ct] = __builtin_amdgcn_mfma_f32_16x16x32_bf16(a1, b, acc[1][ct], 0, 0, 0);
      }
    }
  }
  // epilogue
#pragma unroll
  for (int ct = 0; ct < 4; ++ct) {
    int col = wc0 + ct * 16 + (lane & 15);
    float bb = bias[col];
#pragma unroll
    for (int rt = 0; rt < 2; ++rt) {
#pragma unroll
      for (int rg = 0; rg < 4; ++rg) {
        int row = row0 + wr0 + rt * 16 + (lane >> 4) * 4 + rg;
        float v = acc[rt][ct][rg] + bb;
        if (MODE == 1) {
          v = fmaxf(v, 0.f);
          atomicAdd(&agg[(size_t)clampi(recv[row]) * 128 + col], v);
        } else {
          if (row < M) {
            if (resid) v += resid[(size_t)row * 128 + col];
            if (relu) v = fmaxf(v, 0.f);
            out[(size_t)row * 128 + col] = v;
          }
        }
      }
    }
  }
}

// ---- fused 3-layer MFMA relation encoder ---------------------------------
template <int K, bool TOGLOBAL>
__device__ __forceinline__ void re_layer(
    const unsigned short (*hIn)[136], unsigned short (*hOut)[136],
    unsigned short (*wt)[72], const float* __restrict__ WTg,
    const float* __restrict__ bias, float* __restrict__ gout,
    int row0, int tid) {
  int lane = tid & 63, w = tid >> 6;
  int wr0 = (w >> 1) * 32, wc0 = (w & 1) * 64;
  f32x4 acc[2][4] = {};
  for (int kc = 0; kc < K; kc += 64) {
    __syncthreads();
#pragma unroll
    for (int i = 0; i < 8; ++i) {
      int idx = i * 256 + tid;
      int n = idx >> 4, kl = (idx & 15) * 4;
      float4 v = *(const float4*)&WTg[(size_t)n * K + kc + kl];
      ushort4 b4; b4.x = f2b(v.x); b4.y = f2b(v.y); b4.z = f2b(v.z); b4.w = f2b(v.w);
      *(ushort4*)&wt[n][kl] = b4;
    }
    __syncthreads();
#pragma unroll
    for (int ks = 0; ks < 64; ks += 32) {
      bf16x8 a0 = *(const bf16x8*)&hIn[wr0 + (lane & 15)][kc + ks + 8 * (lane >> 4)];
      bf16x8 a1 = *(const bf16x8*)&hIn[wr0 + 16 + (lane & 15)][kc + ks + 8 * (lane >> 4)];
#pragma unroll
      for (int ct = 0; ct < 4; ++ct) {
        bf16x8 b = *(const bf16x8*)&wt[wc0 + ct * 16 + (lane & 15)][ks + 8 * (lane >> 4)];
        acc[0][ct] = __builtin_amdgcn_mfma_f32_16x16x32_bf16(a0, b, acc[0][ct], 0, 0, 0);
        acc[1][ct] = __builtin_amdgcn_mfma_f32_16x16x32_bf16(a1, b, acc[1][ct], 0, 0, 0);
      }
    }
  }
#pragma unroll
  for (int ct = 0; ct < 4; ++ct) {
    int col = wc0 + ct * 16 + (lane & 15);
    float bb = bias[col];
#pragma unroll
    for (int rt = 0; rt < 2; ++rt) {
#pragma unroll
      for (int rg = 0; rg < 4; ++rg) {
        int rl = wr0 + rt * 16 + (lane >> 4) * 4 + rg;
        float v = fmaxf(acc[rt][ct][rg] + bb, 0.f);
        if (TOGLOBAL) gout[(size_t)(row0 + rl) * 128 + col] = v;
        else          hOut[rl][col] = f2b(v);
      }
    }
  }
}

__global__ __launch_bounds__(256) void k_rel_enc(
    const float* __restrict__ pin, const int* __restrict__ recv,
    const int* __restrict__ send, const float* __restrict__ pinst,
    const float* __restrict__ w0T, const float* __restrict__ b0,
    const float* __restrict__ w1T, const float* __restrict__ b1,
    const float* __restrict__ w2T, const float* __restrict__ b2,
    float* __restrict__ RE) {
  __shared__ unsigned short hA[64][136];
  __shared__ unsigned short hB[64][136];
  __shared__ unsigned short wt[128][72];
  int tid = threadIdx.x;
  int row0 = blockIdx.x * 64;
  // build layer-0 input: 64 rows x 64 cols (44 real, rest zero)
#pragma unroll
  for (int i = 0; i < 16; ++i) {
    int idx = i * 256 + tid;
    int r = idx >> 6, c = idx & 63;
    int e = row0 + r;
    int rr = clampi(recv[e]), ss = clampi(send[e]);
    const float* pr = pin + (size_t)rr * 16;
    const float* ps = pin + (size_t)ss * 16;
    float v = 0.f;
    if (c < 15) v = pr[c];
    else if (c < 30) v = ps[c - 15];
    else if (c < 32) v = pr[c - 30];
    else if (c < 34) v = ps[c - 32];
    else if (c == 34) {
      float gd = 0.f;
#pragma unroll
      for (int j = 0; j < 8; ++j) {
        float gr = (rr < NP_OBJ) ? pinst[rr * 8 + j] : 0.f;
        float gs = (ss < NP_OBJ) ? pinst[ss * 8 + j] : 0.f;
        gd += fabsf(gr - gs);
      }
      v = gd;
    } else if (c < 44) {
      v = pr[2 + c - 35] - ps[2 + c - 35];
    }
    hA[r][c] = f2b(v);
  }
  re_layer<64, false>(hA, hB, wt, w0T, b0, nullptr, row0, tid);
  re_layer<128, false>(hB, hA, wt, w1T, b1, nullptr, row0, tid);
  re_layer<128, true>(hA, hB, wt, w2T, b2, RE, row0, tid);
}

// ---- final tiny GEMV + clip + outputs ------------------------------------
__global__ void k_predict(const float* __restrict__ h2, const float* __restrict__ w2,
                          const float* __restrict__ b2, const float* __restrict__ state,
                          float* __restrict__ out) {
  int i = blockIdx.x * blockDim.x + threadIdx.x;
  if (i >= NP_OBJ) return;
  float acc0 = b2[0], acc1 = b2[1], acc2 = b2[2];
  const float* h = h2 + (size_t)i * 128;
#pragma unroll 8
  for (int k = 0; k < 128; ++k) {
    float hv = h[k];
    acc0 += hv * w2[k * 3 + 0];
    acc1 += hv * w2[k * 3 + 1];
    acc2 += hv * w2[k * 3 + 2];
  }
  float m[3] = {acc0, acc1, acc2};
#pragma unroll
  for (int d = 0; d < 3; ++d) {
    float cl = fminf(fmaxf(m[d], -100.f), 100.f);
    float pos = state[(size_t)(2 * N_PART + i) * 3 + d] + cl;
    out[i * 3 + d] = pos;
    out[NP_OBJ * 3 + i * 3 + d] = m[d];
  }
}

extern "C" void kernel_launch(void* const* d_in, const int* in_sizes, int n_in,
                              void* d_out, int out_size, void* d_ws, size_t ws_size,
                              hipStream_t stream) {
  const float* state  = (const float*)d_in[0];
  const float* attrs  = (const float*)d_in[1];
  const float* Rr     = (const float*)d_in[2];
  const float* Rs     = (const float*)d_in[3];
  const float* pinst  = (const float*)d_in[4];
  const float* action = (const float*)d_in[5];
  const float* phys   = (const float*)d_in[6];
  const float* pe_w0 = (const float*)d_in[7];  const float* pe_b0 = (const float*)d_in[8];
  const float* pe_w1 = (const float*)d_in[9];  const float* pe_b1 = (const float*)d_in[10];
  const float* pe_w2 = (const float*)d_in[11]; const float* pe_b2 = (const float*)d_in[12];
  const float* re_w0 = (const float*)d_in[13]; const float* re_b0 = (const float*)d_in[14];
  const float* re_w1 = (const float*)d_in[15]; const float* re_b1 = (const float*)d_in[16];
  const float* re_w2 = (const float*)d_in[17]; const float* re_b2 = (const float*)d_in[18];
  const float* pp_w  = (const float*)d_in[19]; const float* pp_b  = (const float*)d_in[20];
  const float* rp_w  = (const float*)d_in[21]; const float* rp_b  = (const float*)d_in[22];
  const float* np_w0 = (const float*)d_in[23]; const float* np_b0 = (const float*)d_in[24];
  const float* np_w1 = (const float*)d_in[25]; const float* np_b1 = (const float*)d_in[26];
  const float* np_w2 = (const float*)d_in[27]; const float* np_b2 = (const float*)d_in[28];

  char* ws = (char*)d_ws;
  size_t off = 0;
  auto alloc = [&](size_t b) { size_t o = off; off += (b + 255) & ~(size_t)255; return o; };
  int*   recv = (int*)(ws + alloc(NREL * 4));
  int*   send = (int*)(ws + alloc(NREL * 4));
  float* pin  = (float*)(ws + alloc((size_t)N_PART * 16 * 4));
  float* t0   = (float*)(ws + alloc((size_t)N_PART * 128 * 4));
  float* t1   = (float*)(ws + alloc((size_t)N_PART * 128 * 4));
  float* PE   = (float*)(ws + alloc((size_t)N_PART * 128 * 4));
  float* RE   = (float*)(ws + alloc((size_t)NREL * 128 * 4));
  float* agg  = (float*)(ws + alloc((size_t)N_PART * 128 * 4));
  float* eA   = (float*)(ws + alloc((size_t)N_PART * 128 * 4));
  float* eB   = (float*)(ws + alloc((size_t)N_PART * 128 * 4));
  float* re_w0T = (float*)(ws + alloc(128 * 64 * 4));
  float* re_w1T = (float*)(ws + alloc(128 * 128 * 4));
  float* re_w2T = (float*)(ws + alloc(128 * 128 * 4));
  float* rp_wT  = (float*)(ws + alloc(128 * 384 * 4));
  float* pp_wT  = (float*)(ws + alloc(128 * 256 * 4));
  float* pe_w1T = (float*)(ws + alloc(128 * 128 * 4));
  float* pe_w2T = (float*)(ws + alloc(128 * 128 * 4));
  float* np_w0T = (float*)(ws + alloc(128 * 128 * 4));
  float* np_w1T = (float*)(ws + alloc(128 * 128 * 4));
  if (off > ws_size) return;  // diagnostic guard: fail numerically, not fault

  k_izero<<<(2 * NREL + 255) / 256, 256, 0, stream>>>(recv, 2 * NREL);
  k_extract_idx<<<(2 * NREL) / 4, 256, 0, stream>>>(Rr, Rs, recv, send);
  k_pinputs<<<(N_PART + 255) / 256, 256, 0, stream>>>(state, attrs, action, phys, pin);

  TW9 tw;
  tw.s[0] = {re_w0, re_w0T, 44, 64};
  tw.s[1] = {re_w1, re_w1T, 128, 128};
  tw.s[2] = {re_w2, re_w2T, 128, 128};
  tw.s[3] = {rp_w,  rp_wT,  384, 384};
  tw.s[4] = {pp_w,  pp_wT,  256, 256};
  tw.s[5] = {pe_w1, pe_w1T, 128, 128};
  tw.s[6] = {pe_w2, pe_w2T, 128, 128};
  tw.s[7] = {np_w0, np_w0T, 128, 128};
  tw.s[8] = {np_w1, np_w1T, 128, 128};
  k_twT<<<9 * 128, 64, 0, stream>>>(tw);

  // particle encoder: f32 K=15 layer, then 2 MFMA layers
  k_gemm0<<<N_PART / 32, 256, 0, stream>>>(pin, 16, 15, N_PART, pe_w0, pe_b0, t0);
  k_mgemm<0, 128><<<N_PART / 64, 256, 0, stream>>>(t0, pe_w1T, N_PART, pe_b1, nullptr, t1, 1,
                                                   nullptr, nullptr, nullptr, nullptr);
  k_mgemm<0, 128><<<N_PART / 64, 256, 0, stream>>>(t1, pe_w2T, N_PART, pe_b2, nullptr, PE, 1,
                                                   nullptr, nullptr, nullptr, nullptr);

  // fused MFMA relation encoder
  k_rel_enc<<<NREL / 64, 256, 0, stream>>>(pin, recv, send, pinst,
                                           re_w0T, re_b0, re_w1T, re_b1, re_w2T, re_b2, RE);

  // propagation x3
  float* ecur = PE;
  float* enext = eA;
  for (int step = 0; step < 3; ++step) {
    k_zero<<<(N_PART * 128 + 255) / 256, 256, 0, stream>>>(agg, N_PART * 128);
    k_mgemm<1, 384><<<NREL / 64, 256, 0, stream>>>(RE, rp_wT, NREL, rp_b, nullptr, nullptr, 1,
                                                   ecur, recv, send, agg);
    k_mgemm<2, 256><<<N_PART / 64, 256, 0, stream>>>(PE, pp_wT, N_PART, pp_b, ecur, enext, 1,
                                                     agg, nullptr, nullptr, nullptr);
    ecur = enext;
    enext = (ecur == eA) ? eB : eA;
  }

  // predictor
  float* h1 = t0;
  float* h2 = t1;
  k_mgemm<0, 128><<<32, 256, 0, stream>>>(ecur, np_w0T, NP_OBJ, np_b0, nullptr, h1, 1,
                                          nullptr, nullptr, nullptr, nullptr);
  k_mgemm<0, 128><<<32, 256, 0, stream>>>(h1, np_w1T, NP_OBJ, np_b1, nullptr, h2, 1,
                                          nullptr, nullptr, nullptr, nullptr);
  k_predict<<<(NP_OBJ + 255) / 256, 256, 0, stream>>>(h2, np_w2, np_b2, state, (float*)d_out);
}

// Round 6
// 188.018 us; speedup vs baseline: 1.9596x; 1.5478x over previous
//
#include <hip/hip_runtime.h>

#define N_PART 2048
#define NP_OBJ 2000
#define NREL 16384

typedef unsigned short u16;
typedef __attribute__((ext_vector_type(8))) short bf16x8;
typedef __attribute__((ext_vector_type(4))) float f32x4;

__device__ __forceinline__ int clampi(int v) {
  return v < 0 ? 0 : (v >= N_PART ? N_PART - 1 : v);
}
__device__ __forceinline__ u16 f2b(float f) {
  union { float f; unsigned int u; } v; v.f = f;
  return (u16)((v.u + 0x7fffu + ((v.u >> 16) & 1u)) >> 16);  // RNE
}
__device__ __forceinline__ float b2f(u16 u) {
  union { unsigned int i; float f; } v; v.i = ((unsigned int)u) << 16; return v.f;
}

// ---- zero helpers --------------------------------------------------------
__global__ __launch_bounds__(256) void k_zero(float* __restrict__ p, int n) {
  int i = blockIdx.x * 256 + threadIdx.x;
  if (i < n) p[i] = 0.f;
}
__global__ __launch_bounds__(256) void k_izero(int* __restrict__ p, int n) {
  int i = blockIdx.x * 256 + threadIdx.x;
  if (i < n) p[i] = 0;
}

// ---- flat streaming one-hot index extraction -----------------------------
// grid MUST be 2048 blocks x 256: exactly 32 iterations per thread.
__global__ __launch_bounds__(256) void k_extract_flat(
    const float* __restrict__ Rr, const float* __restrict__ Rs,
    int* __restrict__ recv /* send = recv + NREL */) {
  const int HALF4 = NREL * (N_PART / 4);  // uint4 count per matrix
  const int STRIDE = 2048 * 256;
  int gid = blockIdx.x * 256 + threadIdx.x;
#pragma unroll 8
  for (int j = 0; j < 32; ++j) {
    int i = j * STRIDE + gid;
    bool second = i >= HALF4;
    const uint4* base = (const uint4*)(second ? Rs : Rr);
    int li = second ? i - HALF4 : i;
    uint4 u = base[li];
    if (u.x | u.y | u.z | u.w) {
      int row = li >> 9;  // 512 uint4 per 2048-float row
      int col = (li & 511) * 4 + (u.x ? 0 : (u.y ? 1 : (u.z ? 2 : 3)));
      recv[(second ? NREL : 0) + row] = col;
    }
  }
}

// ---- build p_inputs [2048][16] f32 (col 15 = pad) ------------------------
__global__ void k_pinputs(const float* __restrict__ state, const float* __restrict__ attrs,
                          const float* __restrict__ action, const float* __restrict__ phys,
                          float* __restrict__ pin) {
  int i = blockIdx.x * blockDim.x + threadIdx.x;
  if (i >= N_PART) return;
  float s0[3], s1[3], s2[3];
#pragma unroll
  for (int d = 0; d < 3; ++d) {
    s0[d] = state[(0 * N_PART + i) * 3 + d];
    s1[d] = state[(1 * N_PART + i) * 3 + d];
    s2[d] = state[(2 * N_PART + i) * 3 + d];
  }
  float* o = pin + (size_t)i * 16;
  o[0] = attrs[i * 2 + 0];
  o[1] = attrs[i * 2 + 1];
#pragma unroll
  for (int d = 0; d < 3; ++d) {
    o[2 + d] = s1[d] - s0[d];
    o[5 + d] = s2[d] - s1[d];
    o[8 + d] = s2[d];
  }
  o[11] = (i < NP_OBJ) ? phys[i] : 0.f;
#pragma unroll
  for (int d = 0; d < 3; ++d) o[12 + d] = action[i * 3 + d];
  o[15] = 0.f;
}

// ---- transpose + bf16-convert weights W[K][128] -> WT[128][Kp] ----------
struct TWSeg { const float* src; u16* dst; int K; int Kp; };
struct TW10 { TWSeg s[10]; };
__global__ __launch_bounds__(64) void k_twTb(TW10 t) {
  int m = blockIdx.x >> 7;
  int n = blockIdx.x & 127;
  TWSeg sg = t.s[m];
  for (int k = threadIdx.x; k < sg.Kp; k += 64) {
    float v = (k < sg.K) ? sg.src[(size_t)k * 128 + n] : 0.f;
    sg.dst[(size_t)n * sg.Kp + k] = f2b(v);
  }
}

// ---- one MFMA MLP layer on a 64-row LDS-resident tile --------------------
// hIn bf16 [64][136]; WTg bf16 [128][K]; out -> hOut (bf16 LDS) or gout (bf16 global).
template <int K, bool TOGLOBAL>
__device__ __forceinline__ void re_layer(
    const u16 (*hIn)[136], u16 (*hOut)[136], u16 (*wt)[72],
    const u16* __restrict__ WTg, const float* __restrict__ bias,
    u16* __restrict__ gout, int row0, int tid) {
  int lane = tid & 63, w = tid >> 6;
  int wr0 = (w >> 1) * 32, wc0 = (w & 1) * 64;
  f32x4 acc[2][4] = {};
  for (int kc = 0; kc < K; kc += 64) {
    __syncthreads();  // protect wt (prev users) / hIn (fully written)
#pragma unroll
    for (int i = 0; i < 4; ++i) {
      int idx = i * 256 + tid;
      int n = idx >> 3, kl8 = (idx & 7) * 8;
      *(bf16x8*)&wt[n][kl8] = *(const bf16x8*)&WTg[(size_t)n * K + kc + kl8];
    }
    __syncthreads();
#pragma unroll
    for (int ks = 0; ks < 64; ks += 32) {
      bf16x8 a0 = *(const bf16x8*)&hIn[wr0 + (lane & 15)][kc + ks + 8 * (lane >> 4)];
      bf16x8 a1 = *(const bf16x8*)&hIn[wr0 + 16 + (lane & 15)][kc + ks + 8 * (lane >> 4)];
#pragma unroll
      for (int ct = 0; ct < 4; ++ct) {
        bf16x8 b = *(const bf16x8*)&wt[wc0 + ct * 16 + (lane & 15)][ks + 8 * (lane >> 4)];
        acc[0][ct] = __builtin_amdgcn_mfma_f32_16x16x32_bf16(a0, b, acc[0][ct], 0, 0, 0);
        acc[1][ct] = __builtin_amdgcn_mfma_f32_16x16x32_bf16(a1, b, acc[1][ct], 0, 0, 0);
      }
    }
  }
  __syncthreads();  // all reads of hIn/hOut-alias done before epilogue writes
#pragma unroll
  for (int ct = 0; ct < 4; ++ct) {
    int col = wc0 + ct * 16 + (lane & 15);
    float bb = bias[col];
#pragma unroll
    for (int rt = 0; rt < 2; ++rt) {
#pragma unroll
      for (int rg = 0; rg < 4; ++rg) {
        int rl = wr0 + rt * 16 + (lane >> 4) * 4 + rg;
        float v = fmaxf(acc[rt][ct][rg] + bb, 0.f);
        if (TOGLOBAL) gout[(size_t)(row0 + rl) * 128 + col] = f2b(v);
        else          hOut[rl][col] = f2b(v);
      }
    }
  }
}

// ---- fused 3-layer particle encoder (pin -> PE bf16) ---------------------
__global__ __launch_bounds__(256) void k_pe_enc(
    const float* __restrict__ pin,
    const u16* __restrict__ w0T, const float* __restrict__ b0,
    const u16* __restrict__ w1T, const float* __restrict__ b1,
    const u16* __restrict__ w2T, const float* __restrict__ b2,
    u16* __restrict__ PE) {
  __shared__ u16 hA[64][136];
  __shared__ u16 hB[64][136];
  __shared__ u16 wt[128][72];
  int tid = threadIdx.x;
  int row0 = blockIdx.x * 64;
#pragma unroll
  for (int i = 0; i < 16; ++i) {
    int idx = i * 256 + tid;
    int r = idx >> 6, c = idx & 63;
    float v = (c < 16) ? pin[(size_t)(row0 + r) * 16 + c] : 0.f;
    hA[r][c] = f2b(v);
  }
  re_layer<64, false>(hA, hB, wt, w0T, b0, nullptr, row0, tid);
  re_layer<128, false>(hB, hA, wt, w1T, b1, nullptr, row0, tid);
  re_layer<128, true>(hA, hB, wt, w2T, b2, PE, row0, tid);
}

// ---- fused 3-layer relation encoder (gathers -> RE bf16) -----------------
__global__ __launch_bounds__(256) void k_rel_enc(
    const float* __restrict__ pin, const int* __restrict__ recv,
    const int* __restrict__ send, const float* __restrict__ pinst,
    const u16* __restrict__ w0T, const float* __restrict__ b0,
    const u16* __restrict__ w1T, const float* __restrict__ b1,
    const u16* __restrict__ w2T, const float* __restrict__ b2,
    u16* __restrict__ RE) {
  __shared__ u16 hA[64][136];
  __shared__ u16 hB[64][136];
  __shared__ u16 wt[128][72];
  int tid = threadIdx.x;
  int row0 = blockIdx.x * 64;
#pragma unroll
  for (int i = 0; i < 16; ++i) {
    int idx = i * 256 + tid;
    int r = idx >> 6, c = idx & 63;
    int e = row0 + r;
    int rr = clampi(recv[e]), ss = clampi(send[e]);
    const float* pr = pin + (size_t)rr * 16;
    const float* ps = pin + (size_t)ss * 16;
    float v = 0.f;
    if (c < 15) v = pr[c];
    else if (c < 30) v = ps[c - 15];
    else if (c < 32) v = pr[c - 30];
    else if (c < 34) v = ps[c - 32];
    else if (c == 34) {
      float gd = 0.f;
#pragma unroll
      for (int j = 0; j < 8; ++j) {
        float gr = (rr < NP_OBJ) ? pinst[rr * 8 + j] : 0.f;
        float gs = (ss < NP_OBJ) ? pinst[ss * 8 + j] : 0.f;
        gd += fabsf(gr - gs);
      }
      v = gd;
    } else if (c < 44) {
      v = pr[2 + c - 35] - ps[2 + c - 35];
    }
    hA[r][c] = f2b(v);
  }
  re_layer<64, false>(hA, hB, wt, w0T, b0, nullptr, row0, tid);
  re_layer<128, false>(hB, hA, wt, w1T, b1, nullptr, row0, tid);
  re_layer<128, true>(hA, hB, wt, w2T, b2, RE, row0, tid);
}

// ---- MFMA GEMM, bf16 operands --------------------------------------------
// MODE 1 (relation propagator, KTOT=384): A row e = [RE[e] | eff[recv[e]] | eff[send[e]]];
//          epilogue relu + atomic scatter-add into aggOut[recv[e]].
// MODE 2 (particle propagator, KTOT=256): A row i = [PE[i] | aggIn[i](f32)];
//          epilogue relu(acc + bias + resid[i]) -> out bf16.
template <int MODE, int KTOT>
__global__ __launch_bounds__(256) void k_mgemm(
    const u16* __restrict__ A, const u16* __restrict__ WT,
    const float* __restrict__ bias,
    const u16* __restrict__ resid, u16* __restrict__ out,
    const u16* __restrict__ eff, const float* __restrict__ aggIn,
    const int* __restrict__ recv, const int* __restrict__ send,
    float* __restrict__ aggOut) {
  __shared__ u16 a_lds[64][72];
  __shared__ u16 wt_lds[128][72];
  int tid = threadIdx.x;
  int lane = tid & 63, w = tid >> 6;
  int wr0 = (w >> 1) * 32, wc0 = (w & 1) * 64;
  int row0 = blockIdx.x * 64;
  f32x4 acc[2][4] = {};
  for (int kc = 0; kc < KTOT; kc += 64) {
    __syncthreads();
    // stage A [64 rows][64 k] bf16
#pragma unroll
    for (int i = 0; i < 2; ++i) {
      int idx = i * 256 + tid;
      int r = idx >> 3, kl8 = (idx & 7) * 8;
      int grow = row0 + r;
      if (MODE == 1) {
        const u16* src;
        if (kc < 128)      src = A + (size_t)grow * 128 + kc;
        else if (kc < 256) src = eff + (size_t)clampi(recv[grow]) * 128 + (kc - 128);
        else               src = eff + (size_t)clampi(send[grow]) * 128 + (kc - 256);
        *(bf16x8*)&a_lds[r][kl8] = *(const bf16x8*)&src[kl8];
      } else {
        if (kc < 128) {
          *(bf16x8*)&a_lds[r][kl8] = *(const bf16x8*)&A[(size_t)grow * 128 + kc + kl8];
        } else {
          const float* fs = aggIn + (size_t)grow * 128 + (kc - 128) + kl8;
          float4 v0 = *(const float4*)&fs[0];
          float4 v1 = *(const float4*)&fs[4];
          bf16x8 t;
          t[0] = (short)f2b(v0.x); t[1] = (short)f2b(v0.y);
          t[2] = (short)f2b(v0.z); t[3] = (short)f2b(v0.w);
          t[4] = (short)f2b(v1.x); t[5] = (short)f2b(v1.y);
          t[6] = (short)f2b(v1.z); t[7] = (short)f2b(v1.w);
          *(bf16x8*)&a_lds[r][kl8] = t;
        }
      }
    }
    // stage WT [128 n][64 k] bf16
#pragma unroll
    for (int i = 0; i < 4; ++i) {
      int idx = i * 256 + tid;
      int n = idx >> 3, kl8 = (idx & 7) * 8;
      *(bf16x8*)&wt_lds[n][kl8] = *(const bf16x8*)&WT[(size_t)n * KTOT + kc + kl8];
    }
    __syncthreads();
#pragma unroll
    for (int ks = 0; ks < 64; ks += 32) {
      bf16x8 a0 = *(const bf16x8*)&a_lds[wr0 + (lane & 15)][ks + 8 * (lane >> 4)];
      bf16x8 a1 = *(const bf16x8*)&a_lds[wr0 + 16 + (lane & 15)][ks + 8 * (lane >> 4)];
#pragma unroll
      for (int ct = 0; ct < 4; ++ct) {
        bf16x8 b = *(const bf16x8*)&wt_lds[wc0 + ct * 16 + (lane & 15)][ks + 8 * (lane >> 4)];
        acc[0][ct] = __builtin_amdgcn_mfma_f32_16x16x32_bf16(a0, b, acc[0][ct], 0, 0, 0);
        acc[1][ct] = __builtin_amdgcn_mfma_f32_16x16x32_bf16(a1, b, acc[1][ct], 0, 0, 0);
      }
    }
  }
#pragma unroll
  for (int ct = 0; ct < 4; ++ct) {
    int col = wc0 + ct * 16 + (lane & 15);
    float bb = bias[col];
#pragma unroll
    for (int rt = 0; rt < 2; ++rt) {
#pragma unroll
      for (int rg = 0; rg < 4; ++rg) {
        int row = row0 + wr0 + rt * 16 + (lane >> 4) * 4 + rg;
        float v = acc[rt][ct][rg] + bb;
        if (MODE == 1) {
          v = fmaxf(v, 0.f);
          atomicAdd(&aggOut[(size_t)clampi(recv[row]) * 128 + col], v);
        } else {
          v += b2f(resid[(size_t)row * 128 + col]);
          v = fmaxf(v, 0.f);
          out[(size_t)row * 128 + col] = f2b(v);
        }
      }
    }
  }
}

// ---- fused predictor: 2 MFMA layers + 3-col GEMV + clip + outputs --------
__global__ __launch_bounds__(256) void k_np(
    const u16* __restrict__ eff,
    const u16* __restrict__ w0T, const float* __restrict__ b0,
    const u16* __restrict__ w1T, const float* __restrict__ b1,
    const float* __restrict__ w2, const float* __restrict__ b2,
    const float* __restrict__ state, float* __restrict__ out) {
  __shared__ u16 hA[64][136];
  __shared__ u16 hB[64][136];
  __shared__ u16 wt[128][72];
  __shared__ float sw2[384];
  int tid = threadIdx.x;
  int row0 = blockIdx.x * 64;
#pragma unroll
  for (int i = 0; i < 4; ++i) {
    int idx = i * 256 + tid;
    int r = idx >> 4, kl8 = (idx & 15) * 8;
    *(bf16x8*)&hA[r][kl8] = *(const bf16x8*)&eff[(size_t)(row0 + r) * 128 + kl8];
  }
  for (int j = tid; j < 384; j += 256) sw2[j] = w2[j];
  re_layer<128, false>(hA, hB, wt, w0T, b0, nullptr, row0, tid);
  re_layer<128, false>(hB, hA, wt, w1T, b1, nullptr, row0, tid);
  __syncthreads();
  int r = tid >> 2, d = tid & 3;
  if (d < 3) {
    int row = row0 + r;
    if (row < NP_OBJ) {
      float acc = b2[d];
#pragma unroll 8
      for (int k = 0; k < 128; ++k) acc += b2f(hA[r][k]) * sw2[k * 3 + d];
      float cl = fminf(fmaxf(acc, -100.f), 100.f);
      out[row * 3 + d] = state[(size_t)(2 * N_PART + row) * 3 + d] + cl;
      out[NP_OBJ * 3 + row * 3 + d] = acc;
    }
  }
}

extern "C" void kernel_launch(void* const* d_in, const int* in_sizes, int n_in,
                              void* d_out, int out_size, void* d_ws, size_t ws_size,
                              hipStream_t stream) {
  const float* state  = (const float*)d_in[0];
  const float* attrs  = (const float*)d_in[1];
  const float* Rr     = (const float*)d_in[2];
  const float* Rs     = (const float*)d_in[3];
  const float* pinst  = (const float*)d_in[4];
  const float* action = (const float*)d_in[5];
  const float* phys   = (const float*)d_in[6];
  const float* pe_w0 = (const float*)d_in[7];  const float* pe_b0 = (const float*)d_in[8];
  const float* pe_w1 = (const float*)d_in[9];  const float* pe_b1 = (const float*)d_in[10];
  const float* pe_w2 = (const float*)d_in[11]; const float* pe_b2 = (const float*)d_in[12];
  const float* re_w0 = (const float*)d_in[13]; const float* re_b0 = (const float*)d_in[14];
  const float* re_w1 = (const float*)d_in[15]; const float* re_b1 = (const float*)d_in[16];
  const float* re_w2 = (const float*)d_in[17]; const float* re_b2 = (const float*)d_in[18];
  const float* pp_w  = (const float*)d_in[19]; const float* pp_b  = (const float*)d_in[20];
  const float* rp_w  = (const float*)d_in[21]; const float* rp_b  = (const float*)d_in[22];
  const float* np_w0 = (const float*)d_in[23]; const float* np_b0 = (const float*)d_in[24];
  const float* np_w1 = (const float*)d_in[25]; const float* np_b1 = (const float*)d_in[26];
  const float* np_w2 = (const float*)d_in[27]; const float* np_b2 = (const float*)d_in[28];

  char* ws = (char*)d_ws;
  size_t off = 0;
  auto alloc = [&](size_t b) { size_t o = off; off += (b + 255) & ~(size_t)255; return o; };
  int* recv = (int*)(ws + alloc(2 * NREL * 4));  // send follows recv
  int* send = recv + NREL;
  float* pin = (float*)(ws + alloc((size_t)N_PART * 16 * 4));
  u16* PE  = (u16*)(ws + alloc((size_t)N_PART * 128 * 2));
  u16* RE  = (u16*)(ws + alloc((size_t)NREL * 128 * 2));
  float* agg = (float*)(ws + alloc((size_t)N_PART * 128 * 4));
  u16* eA  = (u16*)(ws + alloc((size_t)N_PART * 128 * 2));
  u16* eB  = (u16*)(ws + alloc((size_t)N_PART * 128 * 2));
  u16* re_w0T = (u16*)(ws + alloc(128 * 64 * 2));
  u16* re_w1T = (u16*)(ws + alloc(128 * 128 * 2));
  u16* re_w2T = (u16*)(ws + alloc(128 * 128 * 2));
  u16* rp_wT  = (u16*)(ws + alloc(128 * 384 * 2));
  u16* pp_wT  = (u16*)(ws + alloc(128 * 256 * 2));
  u16* pe_w0T = (u16*)(ws + alloc(128 * 64 * 2));
  u16* pe_w1T = (u16*)(ws + alloc(128 * 128 * 2));
  u16* pe_w2T = (u16*)(ws + alloc(128 * 128 * 2));
  u16* np_w0T = (u16*)(ws + alloc(128 * 128 * 2));
  u16* np_w1T = (u16*)(ws + alloc(128 * 128 * 2));
  if (off > ws_size) return;  // diagnostic guard

  k_izero<<<(2 * NREL + 255) / 256, 256, 0, stream>>>(recv, 2 * NREL);
  k_extract_flat<<<2048, 256, 0, stream>>>(Rr, Rs, recv);
  k_pinputs<<<(N_PART + 255) / 256, 256, 0, stream>>>(state, attrs, action, phys, pin);

  TW10 tw;
  tw.s[0] = {re_w0, re_w0T, 44, 64};
  tw.s[1] = {re_w1, re_w1T, 128, 128};
  tw.s[2] = {re_w2, re_w2T, 128, 128};
  tw.s[3] = {rp_w,  rp_wT,  384, 384};
  tw.s[4] = {pp_w,  pp_wT,  256, 256};
  tw.s[5] = {pe_w0, pe_w0T, 15, 64};
  tw.s[6] = {pe_w1, pe_w1T, 128, 128};
  tw.s[7] = {pe_w2, pe_w2T, 128, 128};
  tw.s[8] = {np_w0, np_w0T, 128, 128};
  tw.s[9] = {np_w1, np_w1T, 128, 128};
  k_twTb<<<10 * 128, 64, 0, stream>>>(tw);

  k_pe_enc<<<N_PART / 64, 256, 0, stream>>>(pin, pe_w0T, pe_b0, pe_w1T, pe_b1,
                                            pe_w2T, pe_b2, PE);
  k_rel_enc<<<NREL / 64, 256, 0, stream>>>(pin, recv, send, pinst,
                                           re_w0T, re_b0, re_w1T, re_b1,
                                           re_w2T, re_b2, RE);

  u16* ecur = PE;
  u16* enext = eA;
  for (int step = 0; step < 3; ++step) {
    k_zero<<<(N_PART * 128 + 255) / 256, 256, 0, stream>>>(agg, N_PART * 128);
    k_mgemm<1, 384><<<NREL / 64, 256, 0, stream>>>(RE, rp_wT, rp_b, nullptr, nullptr,
                                                   ecur, nullptr, recv, send, agg);
    k_mgemm<2, 256><<<N_PART / 64, 256, 0, stream>>>(PE, pp_wT, pp_b, ecur, enext,
                                                     nullptr, agg, nullptr, nullptr, nullptr);
    ecur = enext;
    enext = (ecur == eA) ? eB : eA;
  }

  k_np<<<32, 256, 0, stream>>>(ecur, np_w0T, np_b0, np_w1T, np_b1,
                               np_w2, np_b2, state, (float*)d_out);
}

// Round 7
// 149.254 us; speedup vs baseline: 2.4685x; 1.2597x over previous
//
#include <hip/hip_runtime.h>

#define N_PART 2048
#define NP_OBJ 2000
#define NREL 16384

typedef unsigned short u16;
typedef __attribute__((ext_vector_type(8))) short bf16x8;
typedef __attribute__((ext_vector_type(4))) float f32x4;

__device__ __forceinline__ int clampi(int v) {
  return v < 0 ? 0 : (v >= N_PART ? N_PART - 1 : v);
}
__device__ __forceinline__ u16 f2b(float f) {
  union { float f; unsigned int u; } v; v.f = f;
  return (u16)((v.u + 0x7fffu + ((v.u >> 16) & 1u)) >> 16);  // RNE
}
__device__ __forceinline__ float b2f(u16 u) {
  union { unsigned int i; float f; } v; v.i = ((unsigned int)u) << 16; return v.f;
}

// ---- zero helper ---------------------------------------------------------
__global__ __launch_bounds__(256) void k_zero(float* __restrict__ p, int n) {
  int i = blockIdx.x * 256 + threadIdx.x;
  if (i < n) p[i] = 0.f;
}

// ---- one-hot index extraction: one wave per row, batched loads -----------
// Row = 2048 f32 = 8192 B = 64 lanes x 8 x uint4. All 8 loads issued before
// any use -> single vmcnt wait, one OR-test, the unique nonzero lane writes.
__global__ __launch_bounds__(256) void k_extract_wave(
    const float* __restrict__ Rr, const float* __restrict__ Rs,
    int* __restrict__ recv /* send = recv + NREL */) {
  int wid = blockIdx.x * 4 + (threadIdx.x >> 6);   // 0 .. 2*NREL-1
  int lane = threadIdx.x & 63;
  bool second = wid >= NREL;
  int row = second ? wid - NREL : wid;
  const uint4* p = (const uint4*)((second ? Rs : Rr) + (size_t)row * N_PART) + lane;
  uint4 v[8];
#pragma unroll
  for (int k = 0; k < 8; ++k) v[k] = p[k * 64];
  unsigned m = 0;
#pragma unroll
  for (int k = 0; k < 8; ++k) m |= (v[k].x | v[k].y | v[k].z | v[k].w);
  if (m) {
    int col = 0;
#pragma unroll
    for (int k = 0; k < 8; ++k) {
      if (v[k].x) col = (k * 64 + lane) * 4 + 0;
      if (v[k].y) col = (k * 64 + lane) * 4 + 1;
      if (v[k].z) col = (k * 64 + lane) * 4 + 2;
      if (v[k].w) col = (k * 64 + lane) * 4 + 3;
    }
    recv[(second ? NREL : 0) + row] = col;
  }
}

// ---- build p_inputs [2048][16] f32 (col 15 = pad) ------------------------
__global__ void k_pinputs(const float* __restrict__ state, const float* __restrict__ attrs,
                          const float* __restrict__ action, const float* __restrict__ phys,
                          float* __restrict__ pin) {
  int i = blockIdx.x * blockDim.x + threadIdx.x;
  if (i >= N_PART) return;
  float s0[3], s1[3], s2[3];
#pragma unroll
  for (int d = 0; d < 3; ++d) {
    s0[d] = state[(0 * N_PART + i) * 3 + d];
    s1[d] = state[(1 * N_PART + i) * 3 + d];
    s2[d] = state[(2 * N_PART + i) * 3 + d];
  }
  float* o = pin + (size_t)i * 16;
  o[0] = attrs[i * 2 + 0];
  o[1] = attrs[i * 2 + 1];
#pragma unroll
  for (int d = 0; d < 3; ++d) {
    o[2 + d] = s1[d] - s0[d];
    o[5 + d] = s2[d] - s1[d];
    o[8 + d] = s2[d];
  }
  o[11] = (i < NP_OBJ) ? phys[i] : 0.f;
#pragma unroll
  for (int d = 0; d < 3; ++d) o[12 + d] = action[i * 3 + d];
  o[15] = 0.f;
}

// ---- transpose + bf16-convert weights W[K][128] -> WT[128][Kp] ----------
struct TWSeg { const float* src; u16* dst; int K; int Kp; };
struct TW10 { TWSeg s[10]; };
__global__ __launch_bounds__(64) void k_twTb(TW10 t) {
  int m = blockIdx.x >> 7;
  int n = blockIdx.x & 127;
  TWSeg sg = t.s[m];
  for (int k = threadIdx.x; k < sg.Kp; k += 64) {
    float v = (k < sg.K) ? sg.src[(size_t)k * 128 + n] : 0.f;
    sg.dst[(size_t)n * sg.Kp + k] = f2b(v);
  }
}

// ---- one MFMA MLP layer on a 64-row LDS-resident tile --------------------
template <int K, bool TOGLOBAL>
__device__ __forceinline__ void re_layer(
    const u16 (*hIn)[136], u16 (*hOut)[136], u16 (*wt)[72],
    const u16* __restrict__ WTg, const float* __restrict__ bias,
    u16* __restrict__ gout, int row0, int tid) {
  int lane = tid & 63, w = tid >> 6;
  int wr0 = (w >> 1) * 32, wc0 = (w & 1) * 64;
  f32x4 acc[2][4] = {};
  for (int kc = 0; kc < K; kc += 64) {
    __syncthreads();
#pragma unroll
    for (int i = 0; i < 4; ++i) {
      int idx = i * 256 + tid;
      int n = idx >> 3, kl8 = (idx & 7) * 8;
      *(bf16x8*)&wt[n][kl8] = *(const bf16x8*)&WTg[(size_t)n * K + kc + kl8];
    }
    __syncthreads();
#pragma unroll
    for (int ks = 0; ks < 64; ks += 32) {
      bf16x8 a0 = *(const bf16x8*)&hIn[wr0 + (lane & 15)][kc + ks + 8 * (lane >> 4)];
      bf16x8 a1 = *(const bf16x8*)&hIn[wr0 + 16 + (lane & 15)][kc + ks + 8 * (lane >> 4)];
#pragma unroll
      for (int ct = 0; ct < 4; ++ct) {
        bf16x8 b = *(const bf16x8*)&wt[wc0 + ct * 16 + (lane & 15)][ks + 8 * (lane >> 4)];
        acc[0][ct] = __builtin_amdgcn_mfma_f32_16x16x32_bf16(a0, b, acc[0][ct], 0, 0, 0);
        acc[1][ct] = __builtin_amdgcn_mfma_f32_16x16x32_bf16(a1, b, acc[1][ct], 0, 0, 0);
      }
    }
  }
  __syncthreads();
#pragma unroll
  for (int ct = 0; ct < 4; ++ct) {
    int col = wc0 + ct * 16 + (lane & 15);
    float bb = bias[col];
#pragma unroll
    for (int rt = 0; rt < 2; ++rt) {
#pragma unroll
      for (int rg = 0; rg < 4; ++rg) {
        int rl = wr0 + rt * 16 + (lane >> 4) * 4 + rg;
        float v = fmaxf(acc[rt][ct][rg] + bb, 0.f);
        if (TOGLOBAL) gout[(size_t)(row0 + rl) * 128 + col] = f2b(v);
        else          hOut[rl][col] = f2b(v);
      }
    }
  }
}

// ---- fused 3-layer particle encoder (pin -> PE bf16) ---------------------
__global__ __launch_bounds__(256) void k_pe_enc(
    const float* __restrict__ pin,
    const u16* __restrict__ w0T, const float* __restrict__ b0,
    const u16* __restrict__ w1T, const float* __restrict__ b1,
    const u16* __restrict__ w2T, const float* __restrict__ b2,
    u16* __restrict__ PE) {
  __shared__ u16 hA[64][136];
  __shared__ u16 hB[64][136];
  __shared__ u16 wt[128][72];
  int tid = threadIdx.x;
  int row0 = blockIdx.x * 64;
#pragma unroll
  for (int i = 0; i < 16; ++i) {
    int idx = i * 256 + tid;
    int r = idx >> 6, c = idx & 63;
    float v = (c < 16) ? pin[(size_t)(row0 + r) * 16 + c] : 0.f;
    hA[r][c] = f2b(v);
  }
  re_layer<64, false>(hA, hB, wt, w0T, b0, nullptr, row0, tid);
  re_layer<128, false>(hB, hA, wt, w1T, b1, nullptr, row0, tid);
  re_layer<128, true>(hA, hB, wt, w2T, b2, PE, row0, tid);
}

// ---- fused 3-layer relation encoder (gathers -> RE bf16) -----------------
__global__ __launch_bounds__(256) void k_rel_enc(
    const float* __restrict__ pin, const int* __restrict__ recv,
    const int* __restrict__ send, const float* __restrict__ pinst,
    const u16* __restrict__ w0T, const float* __restrict__ b0,
    const u16* __restrict__ w1T, const float* __restrict__ b1,
    const u16* __restrict__ w2T, const float* __restrict__ b2,
    u16* __restrict__ RE) {
  __shared__ u16 hA[64][136];
  __shared__ u16 hB[64][136];
  __shared__ u16 wt[128][72];
  int tid = threadIdx.x;
  int row0 = blockIdx.x * 64;
#pragma unroll
  for (int i = 0; i < 16; ++i) {
    int idx = i * 256 + tid;
    int r = idx >> 6, c = idx & 63;
    int e = row0 + r;
    int rr = clampi(recv[e]), ss = clampi(send[e]);
    const float* pr = pin + (size_t)rr * 16;
    const float* ps = pin + (size_t)ss * 16;
    float v = 0.f;
    if (c < 15) v = pr[c];
    else if (c < 30) v = ps[c - 15];
    else if (c < 32) v = pr[c - 30];
    else if (c < 34) v = ps[c - 32];
    else if (c == 34) {
      float gd = 0.f;
#pragma unroll
      for (int j = 0; j < 8; ++j) {
        float gr = (rr < NP_OBJ) ? pinst[rr * 8 + j] : 0.f;
        float gs = (ss < NP_OBJ) ? pinst[ss * 8 + j] : 0.f;
        gd += fabsf(gr - gs);
      }
      v = gd;
    } else if (c < 44) {
      v = pr[2 + c - 35] - ps[2 + c - 35];
    }
    hA[r][c] = f2b(v);
  }
  re_layer<64, false>(hA, hB, wt, w0T, b0, nullptr, row0, tid);
  re_layer<128, false>(hB, hA, wt, w1T, b1, nullptr, row0, tid);
  re_layer<128, true>(hA, hB, wt, w2T, b2, RE, row0, tid);
}

// ---- MFMA GEMM, 32-row tiles (2+ blocks/CU) ------------------------------
// MODE 1 (KTOT=384): A row e = [RE[e] | eff[recv[e]] | eff[send[e]]];
//          epilogue relu + atomic scatter-add into aggOut[recv[e]].
// MODE 2 (KTOT=256): A row i = [PE[i] | aggIn[i](f32)]; stager writes 0 back
//          to aggIn (self-clean for next step); epilogue relu(+bias+resid)->bf16.
template <int MODE, int KTOT>
__global__ __launch_bounds__(256) void k_mgemm32(
    const u16* __restrict__ A, const u16* __restrict__ WT,
    const float* __restrict__ bias,
    const u16* __restrict__ resid, u16* __restrict__ out,
    const u16* __restrict__ eff, float* __restrict__ aggIn,
    const int* __restrict__ recv, const int* __restrict__ send,
    float* __restrict__ aggOut) {
  __shared__ u16 a_lds[32][72];
  __shared__ u16 wt_lds[128][72];
  int tid = threadIdx.x;
  int lane = tid & 63, w = tid >> 6;
  int wr0 = (w >> 1) * 16, wc0 = (w & 1) * 64;
  int row0 = blockIdx.x * 32;
  f32x4 acc[4] = {};
  for (int kc = 0; kc < KTOT; kc += 64) {
    __syncthreads();
    // stage A [32 rows][64 k] bf16 : one bf16x8 per thread
    {
      int r = tid >> 3, kl8 = (tid & 7) * 8;
      int grow = row0 + r;
      if (MODE == 1) {
        const u16* src;
        if (kc < 128)      src = A + (size_t)grow * 128 + kc;
        else if (kc < 256) src = eff + (size_t)clampi(recv[grow]) * 128 + (kc - 128);
        else               src = eff + (size_t)clampi(send[grow]) * 128 + (kc - 256);
        *(bf16x8*)&a_lds[r][kl8] = *(const bf16x8*)&src[kl8];
      } else {
        if (kc < 128) {
          *(bf16x8*)&a_lds[r][kl8] = *(const bf16x8*)&A[(size_t)grow * 128 + kc + kl8];
        } else {
          float* fs = aggIn + (size_t)grow * 128 + (kc - 128) + kl8;
          float4 v0 = *(const float4*)&fs[0];
          float4 v1 = *(const float4*)&fs[4];
          bf16x8 t;
          t[0] = (short)f2b(v0.x); t[1] = (short)f2b(v0.y);
          t[2] = (short)f2b(v0.z); t[3] = (short)f2b(v0.w);
          t[4] = (short)f2b(v1.x); t[5] = (short)f2b(v1.y);
          t[6] = (short)f2b(v1.z); t[7] = (short)f2b(v1.w);
          *(bf16x8*)&a_lds[r][kl8] = t;
          float4 z = make_float4(0.f, 0.f, 0.f, 0.f);
          *(float4*)&fs[0] = z;  // self-clean agg for next step
          *(float4*)&fs[4] = z;
        }
      }
    }
    // stage WT [128 n][64 k] bf16
#pragma unroll
    for (int i = 0; i < 4; ++i) {
      int idx = i * 256 + tid;
      int n = idx >> 3, kl8 = (idx & 7) * 8;
      *(bf16x8*)&wt_lds[n][kl8] = *(const bf16x8*)&WT[(size_t)n * KTOT + kc + kl8];
    }
    __syncthreads();
#pragma unroll
    for (int ks = 0; ks < 64; ks += 32) {
      bf16x8 a0 = *(const bf16x8*)&a_lds[wr0 + (lane & 15)][ks + 8 * (lane >> 4)];
#pragma unroll
      for (int ct = 0; ct < 4; ++ct) {
        bf16x8 b = *(const bf16x8*)&wt_lds[wc0 + ct * 16 + (lane & 15)][ks + 8 * (lane >> 4)];
        acc[ct] = __builtin_amdgcn_mfma_f32_16x16x32_bf16(a0, b, acc[ct], 0, 0, 0);
      }
    }
  }
  int rbase = row0 + wr0 + (lane >> 4) * 4;
  int dst[4];
#pragma unroll
  for (int rg = 0; rg < 4; ++rg)
    dst[rg] = (MODE == 1) ? clampi(recv[rbase + rg]) : 0;
#pragma unroll
  for (int ct = 0; ct < 4; ++ct) {
    int col = wc0 + ct * 16 + (lane & 15);
    float bb = bias[col];
#pragma unroll
    for (int rg = 0; rg < 4; ++rg) {
      int row = rbase + rg;
      float v = acc[ct][rg] + bb;
      if (MODE == 1) {
        v = fmaxf(v, 0.f);
        atomicAdd(&aggOut[(size_t)dst[rg] * 128 + col], v);
      } else {
        v += b2f(resid[(size_t)row * 128 + col]);
        v = fmaxf(v, 0.f);
        out[(size_t)row * 128 + col] = f2b(v);
      }
    }
  }
}

// ---- fused predictor: 2 MFMA layers + 3-col GEMV + clip + outputs --------
__global__ __launch_bounds__(256) void k_np(
    const u16* __restrict__ eff,
    const u16* __restrict__ w0T, const float* __restrict__ b0,
    const u16* __restrict__ w1T, const float* __restrict__ b1,
    const float* __restrict__ w2, const float* __restrict__ b2,
    const float* __restrict__ state, float* __restrict__ out) {
  __shared__ u16 hA[64][136];
  __shared__ u16 hB[64][136];
  __shared__ u16 wt[128][72];
  __shared__ float sw2[384];
  int tid = threadIdx.x;
  int row0 = blockIdx.x * 64;
#pragma unroll
  for (int i = 0; i < 4; ++i) {
    int idx = i * 256 + tid;
    int r = idx >> 4, kl8 = (idx & 15) * 8;
    *(bf16x8*)&hA[r][kl8] = *(const bf16x8*)&eff[(size_t)(row0 + r) * 128 + kl8];
  }
  for (int j = tid; j < 384; j += 256) sw2[j] = w2[j];
  re_layer<128, false>(hA, hB, wt, w0T, b0, nullptr, row0, tid);
  re_layer<128, false>(hB, hA, wt, w1T, b1, nullptr, row0, tid);
  __syncthreads();
  int r = tid >> 2, d = tid & 3;
  if (d < 3) {
    int row = row0 + r;
    if (row < NP_OBJ) {
      float acc = b2[d];
#pragma unroll 8
      for (int k = 0; k < 128; ++k) acc += b2f(hA[r][k]) * sw2[k * 3 + d];
      float cl = fminf(fmaxf(acc, -100.f), 100.f);
      out[row * 3 + d] = state[(size_t)(2 * N_PART + row) * 3 + d] + cl;
      out[NP_OBJ * 3 + row * 3 + d] = acc;
    }
  }
}

extern "C" void kernel_launch(void* const* d_in, const int* in_sizes, int n_in,
                              void* d_out, int out_size, void* d_ws, size_t ws_size,
                              hipStream_t stream) {
  const float* state  = (const float*)d_in[0];
  const float* attrs  = (const float*)d_in[1];
  const float* Rr     = (const float*)d_in[2];
  const float* Rs     = (const float*)d_in[3];
  const float* pinst  = (const float*)d_in[4];
  const float* action = (const float*)d_in[5];
  const float* phys   = (const float*)d_in[6];
  const float* pe_w0 = (const float*)d_in[7];  const float* pe_b0 = (const float*)d_in[8];
  const float* pe_w1 = (const float*)d_in[9];  const float* pe_b1 = (const float*)d_in[10];
  const float* pe_w2 = (const float*)d_in[11]; const float* pe_b2 = (const float*)d_in[12];
  const float* re_w0 = (const float*)d_in[13]; const float* re_b0 = (const float*)d_in[14];
  const float* re_w1 = (const float*)d_in[15]; const float* re_b1 = (const float*)d_in[16];
  const float* re_w2 = (const float*)d_in[17]; const float* re_b2 = (const float*)d_in[18];
  const float* pp_w  = (const float*)d_in[19]; const float* pp_b  = (const float*)d_in[20];
  const float* rp_w  = (const float*)d_in[21]; const float* rp_b  = (const float*)d_in[22];
  const float* np_w0 = (const float*)d_in[23]; const float* np_b0 = (const float*)d_in[24];
  const float* np_w1 = (const float*)d_in[25]; const float* np_b1 = (const float*)d_in[26];
  const float* np_w2 = (const float*)d_in[27]; const float* np_b2 = (const float*)d_in[28];

  char* ws = (char*)d_ws;
  size_t off = 0;
  auto alloc = [&](size_t b) { size_t o = off; off += (b + 255) & ~(size_t)255; return o; };
  int* recv = (int*)(ws + alloc(2 * NREL * 4));  // send follows recv
  int* send = recv + NREL;
  float* pin = (float*)(ws + alloc((size_t)N_PART * 16 * 4));
  u16* PE  = (u16*)(ws + alloc((size_t)N_PART * 128 * 2));
  u16* RE  = (u16*)(ws + alloc((size_t)NREL * 128 * 2));
  float* agg = (float*)(ws + alloc((size_t)N_PART * 128 * 4));
  u16* eA  = (u16*)(ws + alloc((size_t)N_PART * 128 * 2));
  u16* eB  = (u16*)(ws + alloc((size_t)N_PART * 128 * 2));
  u16* re_w0T = (u16*)(ws + alloc(128 * 64 * 2));
  u16* re_w1T = (u16*)(ws + alloc(128 * 128 * 2));
  u16* re_w2T = (u16*)(ws + alloc(128 * 128 * 2));
  u16* rp_wT  = (u16*)(ws + alloc(128 * 384 * 2));
  u16* pp_wT  = (u16*)(ws + alloc(128 * 256 * 2));
  u16* pe_w0T = (u16*)(ws + alloc(128 * 64 * 2));
  u16* pe_w1T = (u16*)(ws + alloc(128 * 128 * 2));
  u16* pe_w2T = (u16*)(ws + alloc(128 * 128 * 2));
  u16* np_w0T = (u16*)(ws + alloc(128 * 128 * 2));
  u16* np_w1T = (u16*)(ws + alloc(128 * 128 * 2));
  if (off > ws_size) return;  // diagnostic guard

  k_extract_wave<<<(2 * NREL) / 4, 256, 0, stream>>>(Rr, Rs, recv);
  k_pinputs<<<(N_PART + 255) / 256, 256, 0, stream>>>(state, attrs, action, phys, pin);

  TW10 tw;
  tw.s[0] = {re_w0, re_w0T, 44, 64};
  tw.s[1] = {re_w1, re_w1T, 128, 128};
  tw.s[2] = {re_w2, re_w2T, 128, 128};
  tw.s[3] = {rp_w,  rp_wT,  384, 384};
  tw.s[4] = {pp_w,  pp_wT,  256, 256};
  tw.s[5] = {pe_w0, pe_w0T, 15, 64};
  tw.s[6] = {pe_w1, pe_w1T, 128, 128};
  tw.s[7] = {pe_w2, pe_w2T, 128, 128};
  tw.s[8] = {np_w0, np_w0T, 128, 128};
  tw.s[9] = {np_w1, np_w1T, 128, 128};
  k_twTb<<<10 * 128, 64, 0, stream>>>(tw);

  k_pe_enc<<<N_PART / 64, 256, 0, stream>>>(pin, pe_w0T, pe_b0, pe_w1T, pe_b1,
                                            pe_w2T, pe_b2, PE);
  k_rel_enc<<<NREL / 64, 256, 0, stream>>>(pin, recv, send, pinst,
                                           re_w0T, re_b0, re_w1T, re_b1,
                                           re_w2T, re_b2, RE);

  // agg must be zero before first prop step (pp self-cleans it afterwards)
  k_zero<<<(N_PART * 128) / 256, 256, 0, stream>>>(agg, N_PART * 128);

  u16* ecur = PE;
  u16* enext = eA;
  for (int step = 0; step < 3; ++step) {
    k_mgemm32<1, 384><<<NREL / 32, 256, 0, stream>>>(RE, rp_wT, rp_b, nullptr, nullptr,
                                                     ecur, nullptr, recv, send, agg);
    k_mgemm32<2, 256><<<N_PART / 32, 256, 0, stream>>>(PE, pp_wT, pp_b, ecur, enext,
                                                       nullptr, agg, nullptr, nullptr, nullptr);
    ecur = enext;
    enext = (ecur == eA) ? eB : eA;
  }

  k_np<<<32, 256, 0, stream>>>(ecur, np_w0T, np_b0, np_w1T, np_b1,
                               np_w2, np_b2, state, (float*)d_out);
}

// Round 8
// 131.421 us; speedup vs baseline: 2.8035x; 1.1357x over previous
//
#include <hip/hip_runtime.h>

#define N_PART 2048
#define NP_OBJ 2000
#define NREL 16384

typedef unsigned short u16;
typedef __attribute__((ext_vector_type(8))) short bf16x8;
typedef __attribute__((ext_vector_type(4))) float f32x4;

__device__ __forceinline__ int clampi(int v) {
  return v < 0 ? 0 : (v >= N_PART ? N_PART - 1 : v);
}
__device__ __forceinline__ u16 f2b(float f) {
  union { float f; unsigned int u; } v; v.f = f;
  return (u16)((v.u + 0x7fffu + ((v.u >> 16) & 1u)) >> 16);  // RNE
}
__device__ __forceinline__ float b2f(u16 u) {
  union { unsigned int i; float f; } v; v.i = ((unsigned int)u) << 16; return v.f;
}

struct TWSeg { const float* src; u16* dst; int K; int Kp; };
struct TW10 { TWSeg s[10]; };

// ---- front kernel: extract (branch-free) + weight transpose + pinputs + agg zero
#define NB_EXT 8192
#define NB_TW  320
#define NB_PIN 8
#define NB_AGZ 8
__global__ __launch_bounds__(256) void k_front(
    const float* __restrict__ Rr, const float* __restrict__ Rs,
    int* __restrict__ recv /* send = recv + NREL */, TW10 tw,
    const float* __restrict__ state, const float* __restrict__ attrs,
    const float* __restrict__ action, const float* __restrict__ phys,
    float* __restrict__ pin, float* __restrict__ agg) {
  int b = blockIdx.x;
  int tid = threadIdx.x;
  if (b < NB_EXT) {
    // ---- one-hot extraction: one wave per row, branch-free ----
    int wid = b * 4 + (tid >> 6);          // 0 .. 2*NREL-1
    int lane = tid & 63;
    bool second = wid >= NREL;
    int row = second ? wid - NREL : wid;
    const uint4* p = (const uint4*)((second ? Rs : Rr) + (size_t)row * N_PART) + lane;
    uint4 v[8];
#pragma unroll
    for (int k = 0; k < 8; ++k) v[k] = p[k * 64];
    int col = 0;
#pragma unroll
    for (int k = 0; k < 8; ++k) {
      int base = (k * 64 + lane) * 4;
      if (v[k].x) col = base;        // v_cmp + v_cndmask, branchless
      if (v[k].y) col = base + 1;
      if (v[k].z) col = base + 2;
      if (v[k].w) col = base + 3;
    }
#pragma unroll
    for (int s = 32; s; s >>= 1) col |= __shfl_xor(col, s);
    if (lane == 0) recv[(second ? NREL : 0) + row] = col;
  } else if (b < NB_EXT + NB_TW) {
    // ---- weight transpose + bf16 convert: W[K][128] -> WT[128][Kp] ----
    int b2 = b - NB_EXT;
    TWSeg sg = tw.s[b2 >> 5];
    int n = (b2 & 31) * 4 + (tid >> 6);
    int k0 = tid & 63;
    for (int k = k0; k < sg.Kp; k += 64) {
      float v = (k < sg.K) ? sg.src[(size_t)k * 128 + n] : 0.f;
      sg.dst[(size_t)n * sg.Kp + k] = f2b(v);
    }
  } else if (b < NB_EXT + NB_TW + NB_PIN) {
    // ---- p_inputs [2048][16] ----
    int i = (b - NB_EXT - NB_TW) * 256 + tid;
    float s0[3], s1[3], s2[3];
#pragma unroll
    for (int d = 0; d < 3; ++d) {
      s0[d] = state[(0 * N_PART + i) * 3 + d];
      s1[d] = state[(1 * N_PART + i) * 3 + d];
      s2[d] = state[(2 * N_PART + i) * 3 + d];
    }
    float* o = pin + (size_t)i * 16;
    o[0] = attrs[i * 2 + 0];
    o[1] = attrs[i * 2 + 1];
#pragma unroll
    for (int d = 0; d < 3; ++d) {
      o[2 + d] = s1[d] - s0[d];
      o[5 + d] = s2[d] - s1[d];
      o[8 + d] = s2[d];
    }
    o[11] = (i < NP_OBJ) ? phys[i] : 0.f;
#pragma unroll
    for (int d = 0; d < 3; ++d) o[12 + d] = action[i * 3 + d];
    o[15] = 0.f;
  } else {
    // ---- zero agg (N_PART*128 floats = 65536 float4) ----
    int b3 = b - NB_EXT - NB_TW - NB_PIN;
    float4* a4 = (float4*)agg;
    float4 z = make_float4(0.f, 0.f, 0.f, 0.f);
#pragma unroll
    for (int j = 0; j < 32; ++j) a4[(size_t)j * 2048 + b3 * 256 + tid] = z;
  }
}

// ---- one MFMA MLP layer on a 64-row LDS-resident tile --------------------
template <int K, bool TOGLOBAL>
__device__ __forceinline__ void re_layer(
    const u16 (*hIn)[136], u16 (*hOut)[136], u16 (*wt)[72],
    const u16* __restrict__ WTg, const float* __restrict__ bias,
    u16* __restrict__ gout, int row0, int tid) {
  int lane = tid & 63, w = tid >> 6;
  int wr0 = (w >> 1) * 32, wc0 = (w & 1) * 64;
  f32x4 acc[2][4] = {};
  for (int kc = 0; kc < K; kc += 64) {
    __syncthreads();
#pragma unroll
    for (int i = 0; i < 4; ++i) {
      int idx = i * 256 + tid;
      int n = idx >> 3, kl8 = (idx & 7) * 8;
      *(bf16x8*)&wt[n][kl8] = *(const bf16x8*)&WTg[(size_t)n * K + kc + kl8];
    }
    __syncthreads();
#pragma unroll
    for (int ks = 0; ks < 64; ks += 32) {
      bf16x8 a0 = *(const bf16x8*)&hIn[wr0 + (lane & 15)][kc + ks + 8 * (lane >> 4)];
      bf16x8 a1 = *(const bf16x8*)&hIn[wr0 + 16 + (lane & 15)][kc + ks + 8 * (lane >> 4)];
#pragma unroll
      for (int ct = 0; ct < 4; ++ct) {
        bf16x8 bq = *(const bf16x8*)&wt[wc0 + ct * 16 + (lane & 15)][ks + 8 * (lane >> 4)];
        acc[0][ct] = __builtin_amdgcn_mfma_f32_16x16x32_bf16(a0, bq, acc[0][ct], 0, 0, 0);
        acc[1][ct] = __builtin_amdgcn_mfma_f32_16x16x32_bf16(a1, bq, acc[1][ct], 0, 0, 0);
      }
    }
  }
  __syncthreads();
#pragma unroll
  for (int ct = 0; ct < 4; ++ct) {
    int col = wc0 + ct * 16 + (lane & 15);
    float bb = bias[col];
#pragma unroll
    for (int rt = 0; rt < 2; ++rt) {
#pragma unroll
      for (int rg = 0; rg < 4; ++rg) {
        int rl = wr0 + rt * 16 + (lane >> 4) * 4 + rg;
        float v = fmaxf(acc[rt][ct][rg] + bb, 0.f);
        if (TOGLOBAL) gout[(size_t)(row0 + rl) * 128 + col] = f2b(v);
        else          hOut[rl][col] = f2b(v);
      }
    }
  }
}

// ---- fused encoders: blocks [0,256) relation rows, [256,288) particle rows
__global__ __launch_bounds__(256) void k_enc(
    const float* __restrict__ pin, const int* __restrict__ recv,
    const int* __restrict__ send, const float* __restrict__ pinst,
    const u16* __restrict__ rw0T, const float* __restrict__ rb0,
    const u16* __restrict__ rw1T, const float* __restrict__ rb1,
    const u16* __restrict__ rw2T, const float* __restrict__ rb2,
    const u16* __restrict__ pw0T, const float* __restrict__ pb0,
    const u16* __restrict__ pw1T, const float* __restrict__ pb1,
    const u16* __restrict__ pw2T, const float* __restrict__ pb2,
    u16* __restrict__ RE, u16* __restrict__ PE) {
  __shared__ u16 hA[64][136];
  __shared__ u16 hB[64][136];
  __shared__ u16 wt[128][72];
  int tid = threadIdx.x;
  bool isRel = blockIdx.x < NREL / 64;
  int row0 = (isRel ? blockIdx.x : blockIdx.x - NREL / 64) * 64;
  if (isRel) {
#pragma unroll
    for (int i = 0; i < 16; ++i) {
      int idx = i * 256 + tid;
      int r = idx >> 6, c = idx & 63;
      int e = row0 + r;
      int rr = clampi(recv[e]), ss = clampi(send[e]);
      const float* pr = pin + (size_t)rr * 16;
      const float* ps = pin + (size_t)ss * 16;
      float v = 0.f;
      if (c < 15) v = pr[c];
      else if (c < 30) v = ps[c - 15];
      else if (c < 32) v = pr[c - 30];
      else if (c < 34) v = ps[c - 32];
      else if (c == 34) {
        float gd = 0.f;
#pragma unroll
        for (int j = 0; j < 8; ++j) {
          float gr = (rr < NP_OBJ) ? pinst[rr * 8 + j] : 0.f;
          float gs = (ss < NP_OBJ) ? pinst[ss * 8 + j] : 0.f;
          gd += fabsf(gr - gs);
        }
        v = gd;
      } else if (c < 44) {
        v = pr[2 + c - 35] - ps[2 + c - 35];
      }
      hA[r][c] = f2b(v);
    }
  } else {
#pragma unroll
    for (int i = 0; i < 16; ++i) {
      int idx = i * 256 + tid;
      int r = idx >> 6, c = idx & 63;
      float v = (c < 16) ? pin[(size_t)(row0 + r) * 16 + c] : 0.f;
      hA[r][c] = f2b(v);
    }
  }
  const u16* w0T = isRel ? rw0T : pw0T;  const float* b0 = isRel ? rb0 : pb0;
  const u16* w1T = isRel ? rw1T : pw1T;  const float* b1 = isRel ? rb1 : pb1;
  const u16* w2T = isRel ? rw2T : pw2T;  const float* b2 = isRel ? rb2 : pb2;
  u16* gout = isRel ? RE : PE;
  re_layer<64, false>(hA, hB, wt, w0T, b0, nullptr, row0, tid);
  re_layer<128, false>(hB, hA, wt, w1T, b1, nullptr, row0, tid);
  re_layer<128, true>(hA, hB, wt, w2T, b2, gout, row0, tid);
}

// ---- MFMA GEMM, 32-row tiles ---------------------------------------------
// MODE 1 (KTOT=384): A row e = [RE[e] | eff[recv[e]] | eff[send[e]]];
//          epilogue relu + atomic scatter-add into aggOut[recv[e]].
// MODE 2 (KTOT=256): A row i = [PE[i] | aggIn[i](f32)]; stager zeroes aggIn
//          after read (self-clean); epilogue relu(+bias+resid)->bf16.
template <int MODE, int KTOT>
__global__ __launch_bounds__(256) void k_mgemm32(
    const u16* __restrict__ A, const u16* __restrict__ WT,
    const float* __restrict__ bias,
    const u16* __restrict__ resid, u16* __restrict__ out,
    const u16* __restrict__ eff, float* __restrict__ aggIn,
    const int* __restrict__ recv, const int* __restrict__ send,
    float* __restrict__ aggOut) {
  __shared__ u16 a_lds[32][72];
  __shared__ u16 wt_lds[128][72];
  int tid = threadIdx.x;
  int lane = tid & 63, w = tid >> 6;
  int wr0 = (w >> 1) * 16, wc0 = (w & 1) * 64;
  int row0 = blockIdx.x * 32;
  f32x4 acc[4] = {};
  for (int kc = 0; kc < KTOT; kc += 64) {
    __syncthreads();
    {
      int r = tid >> 3, kl8 = (tid & 7) * 8;
      int grow = row0 + r;
      if (MODE == 1) {
        const u16* src;
        if (kc < 128)      src = A + (size_t)grow * 128 + kc;
        else if (kc < 256) src = eff + (size_t)clampi(recv[grow]) * 128 + (kc - 128);
        else               src = eff + (size_t)clampi(send[grow]) * 128 + (kc - 256);
        *(bf16x8*)&a_lds[r][kl8] = *(const bf16x8*)&src[kl8];
      } else {
        if (kc < 128) {
          *(bf16x8*)&a_lds[r][kl8] = *(const bf16x8*)&A[(size_t)grow * 128 + kc + kl8];
        } else {
          float* fs = aggIn + (size_t)grow * 128 + (kc - 128) + kl8;
          float4 v0 = *(const float4*)&fs[0];
          float4 v1 = *(const float4*)&fs[4];
          bf16x8 t;
          t[0] = (short)f2b(v0.x); t[1] = (short)f2b(v0.y);
          t[2] = (short)f2b(v0.z); t[3] = (short)f2b(v0.w);
          t[4] = (short)f2b(v1.x); t[5] = (short)f2b(v1.y);
          t[6] = (short)f2b(v1.z); t[7] = (short)f2b(v1.w);
          *(bf16x8*)&a_lds[r][kl8] = t;
          float4 z = make_float4(0.f, 0.f, 0.f, 0.f);
          *(float4*)&fs[0] = z;  // self-clean agg for next step
          *(float4*)&fs[4] = z;
        }
      }
    }
#pragma unroll
    for (int i = 0; i < 4; ++i) {
      int idx = i * 256 + tid;
      int n = idx >> 3, kl8 = (idx & 7) * 8;
      *(bf16x8*)&wt_lds[n][kl8] = *(const bf16x8*)&WT[(size_t)n * KTOT + kc + kl8];
    }
    __syncthreads();
#pragma unroll
    for (int ks = 0; ks < 64; ks += 32) {
      bf16x8 a0 = *(const bf16x8*)&a_lds[wr0 + (lane & 15)][ks + 8 * (lane >> 4)];
#pragma unroll
      for (int ct = 0; ct < 4; ++ct) {
        bf16x8 bq = *(const bf16x8*)&wt_lds[wc0 + ct * 16 + (lane & 15)][ks + 8 * (lane >> 4)];
        acc[ct] = __builtin_amdgcn_mfma_f32_16x16x32_bf16(a0, bq, acc[ct], 0, 0, 0);
      }
    }
  }
  int rbase = row0 + wr0 + (lane >> 4) * 4;
  int dst[4];
#pragma unroll
  for (int rg = 0; rg < 4; ++rg)
    dst[rg] = (MODE == 1) ? clampi(recv[rbase + rg]) : 0;
#pragma unroll
  for (int ct = 0; ct < 4; ++ct) {
    int col = wc0 + ct * 16 + (lane & 15);
    float bb = bias[col];
#pragma unroll
    for (int rg = 0; rg < 4; ++rg) {
      int row = rbase + rg;
      float v = acc[ct][rg] + bb;
      if (MODE == 1) {
        v = fmaxf(v, 0.f);
        atomicAdd(&aggOut[(size_t)dst[rg] * 128 + col], v);
      } else {
        v += b2f(resid[(size_t)row * 128 + col]);
        v = fmaxf(v, 0.f);
        out[(size_t)row * 128 + col] = f2b(v);
      }
    }
  }
}

// ---- fused predictor: 2 MFMA layers + 3-col GEMV + clip + outputs --------
__global__ __launch_bounds__(256) void k_np(
    const u16* __restrict__ eff,
    const u16* __restrict__ w0T, const float* __restrict__ b0,
    const u16* __restrict__ w1T, const float* __restrict__ b1,
    const float* __restrict__ w2, const float* __restrict__ b2,
    const float* __restrict__ state, float* __restrict__ out) {
  __shared__ u16 hA[64][136];
  __shared__ u16 hB[64][136];
  __shared__ u16 wt[128][72];
  __shared__ float sw2[384];
  int tid = threadIdx.x;
  int row0 = blockIdx.x * 64;
#pragma unroll
  for (int i = 0; i < 4; ++i) {
    int idx = i * 256 + tid;
    int r = idx >> 4, kl8 = (idx & 15) * 8;
    *(bf16x8*)&hA[r][kl8] = *(const bf16x8*)&eff[(size_t)(row0 + r) * 128 + kl8];
  }
  for (int j = tid; j < 384; j += 256) sw2[j] = w2[j];
  re_layer<128, false>(hA, hB, wt, w0T, b0, nullptr, row0, tid);
  re_layer<128, false>(hB, hA, wt, w1T, b1, nullptr, row0, tid);
  __syncthreads();
  int r = tid >> 2, d = tid & 3;
  if (d < 3) {
    int row = row0 + r;
    if (row < NP_OBJ) {
      float acc = b2[d];
#pragma unroll 8
      for (int k = 0; k < 128; ++k) acc += b2f(hA[r][k]) * sw2[k * 3 + d];
      float cl = fminf(fmaxf(acc, -100.f), 100.f);
      out[row * 3 + d] = state[(size_t)(2 * N_PART + row) * 3 + d] + cl;
      out[NP_OBJ * 3 + row * 3 + d] = acc;
    }
  }
}

extern "C" void kernel_launch(void* const* d_in, const int* in_sizes, int n_in,
                              void* d_out, int out_size, void* d_ws, size_t ws_size,
                              hipStream_t stream) {
  const float* state  = (const float*)d_in[0];
  const float* attrs  = (const float*)d_in[1];
  const float* Rr     = (const float*)d_in[2];
  const float* Rs     = (const float*)d_in[3];
  const float* pinst  = (const float*)d_in[4];
  const float* action = (const float*)d_in[5];
  const float* phys   = (const float*)d_in[6];
  const float* pe_w0 = (const float*)d_in[7];  const float* pe_b0 = (const float*)d_in[8];
  const float* pe_w1 = (const float*)d_in[9];  const float* pe_b1 = (const float*)d_in[10];
  const float* pe_w2 = (const float*)d_in[11]; const float* pe_b2 = (const float*)d_in[12];
  const float* re_w0 = (const float*)d_in[13]; const float* re_b0 = (const float*)d_in[14];
  const float* re_w1 = (const float*)d_in[15]; const float* re_b1 = (const float*)d_in[16];
  const float* re_w2 = (const float*)d_in[17]; const float* re_b2 = (const float*)d_in[18];
  const float* pp_w  = (const float*)d_in[19]; const float* pp_b  = (const float*)d_in[20];
  const float* rp_w  = (const float*)d_in[21]; const float* rp_b  = (const float*)d_in[22];
  const float* np_w0 = (const float*)d_in[23]; const float* np_b0 = (const float*)d_in[24];
  const float* np_w1 = (const float*)d_in[25]; const float* np_b1 = (const float*)d_in[26];
  const float* np_w2 = (const float*)d_in[27]; const float* np_b2 = (const float*)d_in[28];

  char* ws = (char*)d_ws;
  size_t off = 0;
  auto alloc = [&](size_t b) { size_t o = off; off += (b + 255) & ~(size_t)255; return o; };
  int* recv = (int*)(ws + alloc(2 * NREL * 4));  // send follows recv
  int* send = recv + NREL;
  float* pin = (float*)(ws + alloc((size_t)N_PART * 16 * 4));
  u16* PE  = (u16*)(ws + alloc((size_t)N_PART * 128 * 2));
  u16* RE  = (u16*)(ws + alloc((size_t)NREL * 128 * 2));
  float* agg = (float*)(ws + alloc((size_t)N_PART * 128 * 4));
  u16* eA  = (u16*)(ws + alloc((size_t)N_PART * 128 * 2));
  u16* eB  = (u16*)(ws + alloc((size_t)N_PART * 128 * 2));
  u16* re_w0T = (u16*)(ws + alloc(128 * 64 * 2));
  u16* re_w1T = (u16*)(ws + alloc(128 * 128 * 2));
  u16* re_w2T = (u16*)(ws + alloc(128 * 128 * 2));
  u16* rp_wT  = (u16*)(ws + alloc(128 * 384 * 2));
  u16* pp_wT  = (u16*)(ws + alloc(128 * 256 * 2));
  u16* pe_w0T = (u16*)(ws + alloc(128 * 64 * 2));
  u16* pe_w1T = (u16*)(ws + alloc(128 * 128 * 2));
  u16* pe_w2T = (u16*)(ws + alloc(128 * 128 * 2));
  u16* np_w0T = (u16*)(ws + alloc(128 * 128 * 2));
  u16* np_w1T = (u16*)(ws + alloc(128 * 128 * 2));
  if (off > ws_size) return;  // diagnostic guard

  TW10 tw;
  tw.s[0] = {re_w0, re_w0T, 44, 64};
  tw.s[1] = {re_w1, re_w1T, 128, 128};
  tw.s[2] = {re_w2, re_w2T, 128, 128};
  tw.s[3] = {rp_w,  rp_wT,  384, 384};
  tw.s[4] = {pp_w,  pp_wT,  256, 256};
  tw.s[5] = {pe_w0, pe_w0T, 15, 64};
  tw.s[6] = {pe_w1, pe_w1T, 128, 128};
  tw.s[7] = {pe_w2, pe_w2T, 128, 128};
  tw.s[8] = {np_w0, np_w0T, 128, 128};
  tw.s[9] = {np_w1, np_w1T, 128, 128};

  k_front<<<NB_EXT + NB_TW + NB_PIN + NB_AGZ, 256, 0, stream>>>(
      Rr, Rs, recv, tw, state, attrs, action, phys, pin, agg);

  k_enc<<<NREL / 64 + N_PART / 64, 256, 0, stream>>>(
      pin, recv, send, pinst,
      re_w0T, re_b0, re_w1T, re_b1, re_w2T, re_b2,
      pe_w0T, pe_b0, pe_w1T, pe_b1, pe_w2T, pe_b2, RE, PE);

  u16* ecur = PE;
  u16* enext = eA;
  for (int step = 0; step < 3; ++step) {
    k_mgemm32<1, 384><<<NREL / 32, 256, 0, stream>>>(RE, rp_wT, rp_b, nullptr, nullptr,
                                                     ecur, nullptr, recv, send, agg);
    k_mgemm32<2, 256><<<N_PART / 32, 256, 0, stream>>>(PE, pp_wT, pp_b, ecur, enext,
                                                       nullptr, agg, nullptr, nullptr, nullptr);
    ecur = enext;
    enext = (ecur == eA) ? eB : eA;
  }

  k_np<<<32, 256, 0, stream>>>(ecur, np_w0T, np_b0, np_w1T, np_b1,
                               np_w2, np_b2, state, (float*)d_out);
}